// Round 4
// baseline (1904.764 us; speedup 1.0000x reference)
//
#include <hip/hip_runtime.h>
#include <math.h>

// Problem constants
constexpr int BATCH = 4;
constexpr int SEQ   = 4096;
constexpr int DIMC  = 512;
constexpr int NH    = 8;
constexpr int HD    = 64;
constexpr int NLM   = 256;   // landmarks M
constexpr int LWIN  = 16;    // SEQ / NLM
constexpr int KWIN  = 33;
constexpr int BH    = BATCH * NH; // 32

typedef __attribute__((ext_vector_type(8))) short  bfrag;  // 8 bf16 for MFMA A/B
typedef __attribute__((ext_vector_type(4))) float  ffrag;  // MFMA C/D
typedef __attribute__((ext_vector_type(8))) unsigned short us8;
typedef __attribute__((ext_vector_type(4))) unsigned short us4;
typedef unsigned short ush;

__device__ __forceinline__ ush f2bf(float f) {
  unsigned u = __builtin_bit_cast(unsigned, f);
  return (ush)((u + 0x7FFFu + ((u >> 16) & 1u)) >> 16);
}
__device__ __forceinline__ float bf2f(ush h) {
  unsigned u = ((unsigned)h) << 16;
  return __builtin_bit_cast(float, u);
}
__device__ __forceinline__ void splitf(float f, ush& h, ush& l) {
  h = f2bf(f);
  l = f2bf(f - bf2f(h));
}
// async global->LDS, 16B per lane: LDS dest = base + lane*16 (wave-uniform base)
__device__ __forceinline__ void gl_lds16(const ush* g, ush* l) {
  __builtin_amdgcn_global_load_lds(
      (const __attribute__((address_space(1))) void*)g,
      (__attribute__((address_space(3))) void*)l, 16, 0, 0);
}

// ---------------------------------------------------------------------------
// split_flat: fp32 -> (hi, lo) bf16, elementwise (x pre-split). Grid-stride.
// ---------------------------------------------------------------------------
__global__ void split_flat(const float* __restrict__ src, ush* __restrict__ oh,
                           ush* __restrict__ ol, int n4) {
  for (int i = blockIdx.x * 256 + threadIdx.x; i < n4; i += gridDim.x * 256) {
    float4 f = ((const float4*)src)[i];
    us4 h, l;
    float fs[4] = {f.x, f.y, f.z, f.w};
#pragma unroll
    for (int j = 0; j < 4; ++j) {
      ush hh, ll;
      splitf(fs[j], hh, ll);
      h[j] = hh; l[j] = ll;
    }
    ((us4*)oh)[i] = h;
    ((us4*)ol)[i] = l;
  }
}

// ---------------------------------------------------------------------------
// transpose_split_w: in [R][C] fp32 -> out [C][R] hi/lo bf16 (weights)
// ---------------------------------------------------------------------------
__global__ __launch_bounds__(256) void transpose_split_w(const float* __restrict__ in,
                                                         ush* __restrict__ oh,
                                                         ush* __restrict__ ol,
                                                         int R, int C) {
  __shared__ float T[32][33];
  const int tid = threadIdx.x;
  const int c0 = blockIdx.x * 32, r0 = blockIdx.y * 32;
#pragma unroll
  for (int u = 0; u < 4; ++u) {
    int r = (tid >> 5) * 4 + u, cl = tid & 31;
    T[r][cl] = in[(size_t)(r0 + r) * C + c0 + cl];
  }
  __syncthreads();
#pragma unroll
  for (int u = 0; u < 4; ++u) {
    int cl = (tid >> 5) * 4 + u, rl = tid & 31;
    float f = T[rl][cl];
    ush h, l; splitf(f, h, l);
    size_t o = (size_t)(c0 + cl) * R + r0 + rl;
    oh[o] = h; ol[o] = l;
  }
}

// ---------------------------------------------------------------------------
// K1: qkv MFMA GEMM — ROUND-8: 2-product split (x split, W hi-only; dropped
// x_hi@W_lo term ~1.8e-3 per elem == same order as bf16 output rounding).
// BM=BN=128, BK=32, 256 thr, LDS 30KB. Epilogue: q/k bf16 + landmark pooling;
// v written DIRECTLY TRANSPOSED (vT [bh][d][n]) — vT_cvt kernel eliminated.
// ---------------------------------------------------------------------------
__global__ __launch_bounds__(256) void qkv_mfma(const ush* __restrict__ xh,
                                                const ush* __restrict__ xl,
                                                const ush* __restrict__ wTh,
                                                ush* __restrict__ q_bf,
                                                ush* __restrict__ k_bf,
                                                ush* __restrict__ vT,
                                                float* __restrict__ qlm,
                                                float* __restrict__ klm) {
  __shared__ ush Ash[128][40], Asl[128][40];
  __shared__ ush Bsh[128][40];
  const int tid = threadIdx.x;
  const int w = tid >> 6, lane = tid & 63;
  const int lm = lane & 15, lq = lane >> 4;
  const int wm = w >> 1, wn = w & 1;
  const int row0 = blockIdx.x * 128, col0 = blockIdx.y * 128;
  const ffrag fz = {0.f, 0.f, 0.f, 0.f};
  ffrag acc[4][4];
#pragma unroll
  for (int i = 0; i < 4; ++i)
#pragma unroll
    for (int j = 0; j < 4; ++j) acc[i][j] = fz;

  const int sm = tid >> 1, skoff = (tid & 1) * 16;
  for (int k0 = 0; k0 < 512; k0 += 32) {
    __syncthreads();
    {
      size_t ao = (size_t)(row0 + sm) * 512 + k0 + skoff;
      *(us8*)&Ash[sm][skoff]     = *(const us8*)&xh[ao];
      *(us8*)&Ash[sm][skoff + 8] = *(const us8*)&xh[ao + 8];
      *(us8*)&Asl[sm][skoff]     = *(const us8*)&xl[ao];
      *(us8*)&Asl[sm][skoff + 8] = *(const us8*)&xl[ao + 8];
      size_t bo = (size_t)(col0 + sm) * 512 + k0 + skoff;
      *(us8*)&Bsh[sm][skoff]     = *(const us8*)&wTh[bo];
      *(us8*)&Bsh[sm][skoff + 8] = *(const us8*)&wTh[bo + 8];
    }
    __syncthreads();
    bfrag ah[4], al[4], bh[4];
#pragma unroll
    for (int mt = 0; mt < 4; ++mt) {
      ah[mt] = *(const bfrag*)&Ash[64 * wm + 16 * mt + lm][8 * lq];
      al[mt] = *(const bfrag*)&Asl[64 * wm + 16 * mt + lm][8 * lq];
    }
#pragma unroll
    for (int nt = 0; nt < 4; ++nt)
      bh[nt] = *(const bfrag*)&Bsh[64 * wn + 16 * nt + lm][8 * lq];
#pragma unroll
    for (int mt = 0; mt < 4; ++mt)
#pragma unroll
      for (int nt = 0; nt < 4; ++nt) {
        acc[mt][nt] = __builtin_amdgcn_mfma_f32_16x16x32_bf16(ah[mt], bh[nt], acc[mt][nt], 0, 0, 0);
        acc[mt][nt] = __builtin_amdgcn_mfma_f32_16x16x32_bf16(al[mt], bh[nt], acc[mt][nt], 0, 0, 0);
      }
  }
  // epilogue
#pragma unroll
  for (int mt = 0; mt < 4; ++mt) {
    int rbase = row0 + 64 * wm + 16 * mt;      // 16-aligned -> single window
    int b = rbase >> 12;
    int ntok_base = rbase & 4095;
    int win = ntok_base >> 4;
#pragma unroll
    for (int nt = 0; nt < 4; ++nt) {
      int n_local = 64 * wn + 16 * nt;          // frag col base (h uniform)
      int col = col0 + n_local + lm;
      int which = col >> 9;                     // 0=q 1=k 2=v
      int h = (col >> 6) & 7;
      int d = col & 63;
      int bh_i = b * NH + h;
      float scale = (which == 0) ? 0.125f : 1.0f;
      float vals[4];
      float s = 0.f;
#pragma unroll
      for (int r = 0; r < 4; ++r) {
        vals[r] = acc[mt][nt][r] * scale;
        s += vals[r];
      }
      if (which == 2) {
        // direct transposed store: vT[bh][d][ntok] (4 contiguous ntok/lane)
        ush* dst = &vT[((size_t)bh_i * HD + d) * SEQ + ntok_base + 4 * lq];
#pragma unroll
        for (int r = 0; r < 4; ++r) dst[r] = f2bf(vals[r]);
      } else {
        ush* dst = which == 0 ? q_bf : k_bf;
#pragma unroll
        for (int r = 0; r < 4; ++r) {
          int ntok = ntok_base + 4 * lq + r;
          dst[((size_t)bh_i * SEQ + ntok) * HD + d] = f2bf(vals[r]);
        }
        s += __shfl_xor(s, 16);
        s += __shfl_xor(s, 32);
        if (lq == 0) {
          float* lmdst = which == 0 ? qlm : klm;
          lmdst[((size_t)bh_i * NLM + win) * HD + d] = s * (1.0f / LWIN);
        }
      }
    }
  }
}

// ---------------------------------------------------------------------------
// K3: attn2 = softmax(qlm @ klm^T) rows -> split bf16 (a2h/a2l)
// ---------------------------------------------------------------------------
__global__ __launch_bounds__(256) void sim2_softmax(const float* __restrict__ qlm,
                                                    const float* __restrict__ klm,
                                                    ush* __restrict__ a2h,
                                                    ush* __restrict__ a2l) {
  int i = blockIdx.x & 255;
  int bh = blockIdx.x >> 8;
  int j = threadIdx.x;
  __shared__ float qrow[64];
  __shared__ float red[256];
  if (j < 64) qrow[j] = qlm[((size_t)bh * NLM + i) * HD + j];
  __syncthreads();
  const float* kr = klm + ((size_t)bh * NLM + j) * HD;
  float s = 0.f;
#pragma unroll
  for (int d = 0; d < 64; d += 4) {
    float4 kv = *(const float4*)&kr[d];
    s += qrow[d] * kv.x + qrow[d + 1] * kv.y + qrow[d + 2] * kv.z + qrow[d + 3] * kv.w;
  }
  red[j] = s; __syncthreads();
  for (int off = 128; off > 0; off >>= 1) {
    if (j < off) red[j] = fmaxf(red[j], red[j + off]);
    __syncthreads();
  }
  float mx = red[0]; __syncthreads();
  float e = expf(s - mx);
  red[j] = e; __syncthreads();
  for (int off = 128; off > 0; off >>= 1) {
    if (j < off) red[j] += red[j + off];
    __syncthreads();
  }
  float val = e / red[0];
  size_t o = ((size_t)bh * NLM + i) * NLM + j;
  ush h, l; splitf(val, h, l);
  a2h[o] = h; a2l[o] = l;
}

// ---------------------------------------------------------------------------
// K4a: per-bh column sums of attn2 (hi plane only), block max.
// attn2 rows are softmax rows -> row sums are exactly 1.
// ---------------------------------------------------------------------------
__global__ __launch_bounds__(256) void colmax(const ush* __restrict__ a2h,
                                              float* __restrict__ red) {
  int bh = blockIdx.x;
  int t = threadIdx.x;
  const size_t base = (size_t)bh * NLM * NLM;
  float cs = 0.f;
  for (int i = 0; i < NLM; ++i) cs += bf2f(a2h[base + (size_t)i * NLM + t]);
  __shared__ float r1[256];
  r1[t] = cs; __syncthreads();
  for (int off = 128; off > 0; off >>= 1) {
    if (t < off) r1[t] = fmaxf(r1[t], r1[t + off]);
    __syncthreads();
  }
  if (t == 0) red[bh] = r1[0];
}

// finalize_scale: also zero-initializes the pinv_fused barrier flags
// (re-zeroed every launch -> graph/replay safe).
__global__ void finalize_scale(float* __restrict__ red, unsigned* __restrict__ bar) {
  int t = threadIdx.x;
  for (int i = t; i < 2048; i += 64) bar[i] = 0u;
  if (t == 0) {
    float m1 = -1e30f;
    for (int i = 0; i < BH; ++i) m1 = fmaxf(m1, red[i]);
    red[64] = 1.0f / m1;   // row-sum max == 1 exactly (softmax rows)
  }
}

// ---------------------------------------------------------------------------
// K4c: z0 = attn2^T * invscale, A-form + B-form splits
// ---------------------------------------------------------------------------
__global__ __launch_bounds__(256) void zinit_split(const ush* __restrict__ a2h,
                                                   const ush* __restrict__ a2l,
                                                   const float* __restrict__ red,
                                                   ush* __restrict__ zAh, ush* __restrict__ zAl,
                                                   ush* __restrict__ zBh, ush* __restrict__ zBl) {
  __shared__ float T[32][33];
  const int tid = threadIdx.x;
  const int bh = blockIdx.z;
  const int j0 = blockIdx.x * 32, i0 = blockIdx.y * 32;
  const float s = red[64];
  const size_t base = (size_t)bh * NLM * NLM;
#pragma unroll
  for (int u = 0; u < 4; ++u) {
    int jl = (tid >> 5) * 4 + u, il = tid & 31;
    size_t o = base + (size_t)(j0 + jl) * NLM + i0 + il;
    float a = (bf2f(a2h[o]) + bf2f(a2l[o])) * s;
    T[jl][il] = a;
    ush h, l; splitf(a, h, l);
    zBh[o] = h; zBl[o] = l;   // zB[j][i] = a2[j][i]*s
  }
  __syncthreads();
#pragma unroll
  for (int u = 0; u < 4; ++u) {
    int il = (tid >> 5) * 4 + u, jl = tid & 31;
    float a = T[jl][il];
    ush h, l; splitf(a, h, l);
    size_t o = base + (size_t)(i0 + il) * NLM + j0 + jl;  // zA[i][j] = a2[j][i]*s
    zAh[o] = h; zAl[o] = l;
  }
}

// ---------------------------------------------------------------------------
// K5 core: one 64x64 tile of C = A@B^T(stored) with split-bf16 planes.
// m97 structure: global_load_lds staging, BK=64. Null lo-pointers skip planes.
// Epilogue: y = coef * (alpha*E1 + beta*E2 - C); outputs row-major (oA) and/or
// transposed B-form (oB). FORCEINLINE ONLY (noinline variant corrupted the
// global_load_lds destination path -> round-2 NaN).
// ---------------------------------------------------------------------------
__device__ __forceinline__ void stage_gemm(
    ush (*S)[2][8][64][8],   // LDS [2][2][8][64][8] = 32 KB
    const ush* Ah, const ush* Al, const ush* Bh, const ush* Bl,
    const ush* E1h, const ush* E1l, const ush* E2h, const ush* E2l,
    ush* oAh, ush* oAl, ush* oBh, ush* oBl,
    int M, int N, int K, float alpha, float beta, float coef,
    int bx, int by, int batch, int tid) {
  const size_t abase = (size_t)batch * M * K;
  const size_t bbase = (size_t)batch * N * K;
  const size_t ebase = (size_t)batch * M * N;
  const int w = tid >> 6, lane = tid & 63;
  const int lm = lane & 15, lq = lane >> 4;
  const int wm = w >> 1, wn = w & 1;
  const int row0 = bx * 64, col0 = by * 64;
  const bool uAl = (Al != nullptr);
  const bool uBl = (Bl != nullptr);
  const ffrag fz = {0.f, 0.f, 0.f, 0.f};
  ffrag acc[2][2] = {{fz, fz}, {fz, fz}};

  const size_t arow = abase + (size_t)(row0 + lane) * K;   // per-lane
  const size_t brow = bbase + (size_t)(col0 + lane) * K;

  for (int k0 = 0; k0 < K; k0 += 64) {
    __syncthreads();
    // wave w stages k-chunks {2w, 2w+1} for A and B (lo planes only if used)
#pragma unroll
    for (int ci = 0; ci < 2; ++ci) {
      int c = 2 * w + ci;
      gl_lds16(&Ah[arow + k0 + 8 * c], &S[0][0][c][0][0]);
      gl_lds16(&Bh[brow + k0 + 8 * c], &S[1][0][c][0][0]);
      if (uAl) gl_lds16(&Al[arow + k0 + 8 * c], &S[0][1][c][0][0]);
      if (uBl) gl_lds16(&Bl[brow + k0 + 8 * c], &S[1][1][c][0][0]);
    }
    __syncthreads();   // compiler emits vmcnt(0) drain here (m97 structure)
#pragma unroll
    for (int ks = 0; ks < 2; ++ks) {
      bfrag ah[2], al[2], bhf[2], blf[2];
#pragma unroll
      for (int mt = 0; mt < 2; ++mt) {
        ah[mt] = *(const bfrag*)&S[0][0][4 * ks + lq][32 * wm + 16 * mt + lm][0];
        if (uAl) al[mt] = *(const bfrag*)&S[0][1][4 * ks + lq][32 * wm + 16 * mt + lm][0];
      }
#pragma unroll
      for (int nt = 0; nt < 2; ++nt) {
        bhf[nt] = *(const bfrag*)&S[1][0][4 * ks + lq][32 * wn + 16 * nt + lm][0];
        if (uBl) blf[nt] = *(const bfrag*)&S[1][1][4 * ks + lq][32 * wn + 16 * nt + lm][0];
      }
#pragma unroll
      for (int mt = 0; mt < 2; ++mt)
#pragma unroll
        for (int nt = 0; nt < 2; ++nt) {
          acc[mt][nt] = __builtin_amdgcn_mfma_f32_16x16x32_bf16(ah[mt], bhf[nt], acc[mt][nt], 0, 0, 0);
          if (uAl) acc[mt][nt] = __builtin_amdgcn_mfma_f32_16x16x32_bf16(al[mt], bhf[nt], acc[mt][nt], 0, 0, 0);
          if (uBl) acc[mt][nt] = __builtin_amdgcn_mfma_f32_16x16x32_bf16(ah[mt], blf[nt], acc[mt][nt], 0, 0, 0);
        }
    }
  }
#pragma unroll
  for (int mt = 0; mt < 2; ++mt)
#pragma unroll
    for (int nt = 0; nt < 2; ++nt) {
      int n = col0 + 32 * wn + 16 * nt + lm;
#pragma unroll
      for (int r = 0; r < 4; ++r) {
        int m = row0 + 32 * wm + 16 * mt + 4 * lq + r;
        float c = acc[mt][nt][r];
        float e = 0.f;
        size_t eo = ebase + (size_t)m * N + n;
        if (E1h) {
          float t = bf2f(E1h[eo]);
          if (E1l) t += bf2f(E1l[eo]);
          e += alpha * t;
        }
        if (E2h) {
          float t = bf2f(E2h[eo]);
          if (E2l) t += bf2f(E2l[eo]);
          e += beta * t;
        }
        float y = coef * (e - c);
        ush h, l; splitf(y, h, l);
        if (oAh) {
          size_t o = ebase + (size_t)m * N + n;
          oAh[o] = h;
          if (oAl) oAl[o] = l;
        }
        if (oBh) {
          size_t o = (size_t)batch * N * M + (size_t)n * M + m;
          oBh[o] = h;
          if (oBl) oBl[o] = l;
        }
      }
    }
}

__global__ __launch_bounds__(256) void bgemm_split(
    const ush* Ah, const ush* Al, const ush* Bh, const ush* Bl,
    const ush* E1h, const ush* E1l, const ush* E2h, const ush* E2l,
    ush* oAh, ush* oAl, ush* oBh, ush* oBl,
    int M, int N, int K, float alpha, float beta, float coef) {
  __shared__ ush S[2][2][8][64][8];
  stage_gemm(S, Ah, Al, Bh, Bl, E1h, E1l, E2h, E2l, oAh, oAl, oBh, oBl,
             M, N, K, alpha, beta, coef, blockIdx.x, blockIdx.y, blockIdx.z,
             threadIdx.x);
}

// ---------------------------------------------------------------------------
// Per-batch 16-block barrier for pinv_fused. SYSTEM-scope fences + atomics:
// guarantees cross-XCD L2 writeback/invalidate around the sync point.
// gen is monotonic (replay-safe); cnt returns to 0 after each barrier;
// finalize_scale re-zeros everything each launch.
// ---------------------------------------------------------------------------
__device__ __forceinline__ void gbar16(unsigned* cnt, unsigned* gen) {
  __syncthreads();
  if (threadIdx.x == 0) {
    unsigned g = __hip_atomic_load(gen, __ATOMIC_RELAXED, __HIP_MEMORY_SCOPE_SYSTEM);
    __threadfence_system();   // release: writeback this XCD's L2
    unsigned old = __hip_atomic_fetch_add(cnt, 1u, __ATOMIC_ACQ_REL, __HIP_MEMORY_SCOPE_SYSTEM);
    if (old == 15u) {
      __hip_atomic_store(cnt, 0u, __ATOMIC_RELAXED, __HIP_MEMORY_SCOPE_SYSTEM);
      __hip_atomic_fetch_add(gen, 1u, __ATOMIC_ACQ_REL, __HIP_MEMORY_SCOPE_SYSTEM);
    } else {
      while (__hip_atomic_load(gen, __ATOMIC_ACQUIRE, __HIP_MEMORY_SCOPE_SYSTEM) == g)
        __builtin_amdgcn_s_sleep(2);
    }
    __threadfence_system();   // acquire: invalidate before reading peers' data
  }
  __syncthreads();
}

// ---------------------------------------------------------------------------
// pinv_fused: entire 6-iteration, 3-stage Newton-Schulz chain in ONE dispatch.
// Grid = 512 (bx 0..3, by 0..3, bz 0..31); LB(256,2) + 32 KB LDS -> 2
// blocks/CU, all co-resident. Per-batch dependencies -> 16-block barriers;
// the 32 chains drift independently (no grid-wide convoy).
//   S1: Y = a2@z              (Y symmetric: row-major only)
//   S2: t2 = 7Y - Y@Y ; U = z@Y   (each block does both tiles)
//   S3: z' = 0.25*(13z - 15U + U@t2)  (A-form + B-form)
// iters 0-3 plain bf16, iter 4 split-arith, iter 5 full split (r1/r3-proven
// precision flow, absmax 0.0039).
// ---------------------------------------------------------------------------
__global__ __launch_bounds__(256, 2) void pinv_fused(
    const ush* a2h, const ush* a2l,
    ush* zA0, ush* zA1, ush* zA2, ush* zA3,
    ush* zB0, ush* zB1, ush* zB2, ush* zB3,
    ush* Y_h, ush* Y_l, ush* t2_h, ush* t2_l, ush* U_h, ush* U_l,
    unsigned* bar) {
  __shared__ ush S[2][2][8][64][8];
  const int tid = threadIdx.x;
  const int b = blockIdx.x;
  const int bx = b & 3, by = (b >> 2) & 3, bz = b >> 4;
  unsigned* cnt = bar + bz * 64;
  unsigned* gen = cnt + 32;

  ush* zc0 = zA0; ush* zc1 = zA1; ush* zc2 = zA2; ush* zc3 = zA3;
  ush* zn0 = zB0; ush* zn1 = zB1; ush* zn2 = zB2; ush* zn3 = zB3;

#pragma unroll 1
  for (int it = 0; it < 6; ++it) {
    const bool zin_s  = (it == 5);   // z input has a valid lo plane
    const bool a2_s   = (it >= 4);   // use a2 lo plane
    const bool mid_s  = (it >= 4);   // Y/t2/U intermediates split
    const bool zout_s = (it >= 4);   // write z split
    // S1: Y = a2 @ z
    stage_gemm(S, a2h, a2_s ? a2l : nullptr, zc2, zin_s ? zc3 : nullptr,
               nullptr, nullptr, nullptr, nullptr,
               Y_h, mid_s ? Y_l : nullptr, nullptr, nullptr,
               256, 256, 256, 0.f, 0.f, -1.f, bx, by, bz, tid);
    gbar16(cnt, gen);
    // S2a: t2 = 7Y - Y@Y  (Y symmetric -> row-major serves as B)
    stage_gemm(S, Y_h, mid_s ? Y_l : nullptr, Y_h, mid_s ? Y_l : nullptr,
               Y_h, mid_s ? Y_l : nullptr, nullptr, nullptr,
               t2_h, mid_s ? t2_l : nullptr, nullptr, nullptr,
               256, 256, 256, 7.f, 0.f, 1.f, bx, by, bz, tid);
    // S2b: U = z @ Y
    stage_gemm(S, zc0, zin_s ? zc1 : nullptr, Y_h, mid_s ? Y_l : nullptr,
               nullptr, nullptr, nullptr, nullptr,
               U_h, mid_s ? U_l : nullptr, nullptr, nullptr,
               256, 256, 256, 0.f, 0.f, -1.f, bx, by, bz, tid);
    gbar16(cnt, gen);
    // S3: z' = 0.25*(13 z - 15 U + U@t2)
    stage_gemm(S, U_h, mid_s ? U_l : nullptr, t2_h, mid_s ? t2_l : nullptr,
               zc0, zin_s ? zc1 : nullptr,      // E1 = z  (alpha = -13)
               U_h, mid_s ? U_l : nullptr,      // E2 = U  (beta  = +15)
               zn0, zout_s ? zn1 : nullptr, zn2, zout_s ? zn3 : nullptr,
               256, 256, 256, -13.f, 15.f, -0.25f, bx, by, bz, tid);
    if (it < 5) gbar16(cnt, gen);
    ush* t;
    t = zc0; zc0 = zn0; zn0 = t;
    t = zc1; zc1 = zn1; zn1 = t;
    t = zc2; zc2 = zn2; zn2 = t;
    t = zc3; zc3 = zn3; zn3 = t;
  }
  // final z (attn2_inv) lands in the zA set (6 swaps).
}

// ---------------------------------------------------------------------------
// K6: sim3 flash via MFMA, no max-subtraction (scores tiny). n-split NCH ways.
// ---------------------------------------------------------------------------
constexpr int NCH = 4;
__global__ __launch_bounds__(256) void sim3_mfma(const float* __restrict__ qlm,
                                                 const ush* __restrict__ k_bf,
                                                 const ush* __restrict__ vT_bf,
                                                 float* __restrict__ O_part,
                                                 float* __restrict__ l_part) {
  constexpr int CHUNK = SEQ / NCH;  // 1024
  __shared__ ush Qs[64][72];
  __shared__ ush Ks[128][72];
  __shared__ ush Vs[64][136];
  __shared__ ush Ps[64][136];
  const int bh = blockIdx.z;
  const int m0 = blockIdx.x * 64;
  const int n_base = blockIdx.y * CHUNK;
  const int tid = threadIdx.x;
  const int w = tid >> 6, lane = tid & 63;
  const int lm = lane & 15, lq = lane >> 4;
  {
    int m = tid >> 2, off = (tid & 3) * 16;
    const float* src = &qlm[((size_t)bh * NLM + m0 + m) * HD + off];
    us8 o0, o1;
#pragma unroll
    for (int j = 0; j < 8; ++j) o0[j] = f2bf(src[j]);
#pragma unroll
    for (int j = 0; j < 8; ++j) o1[j] = f2bf(src[8 + j]);
    *(us8*)&Qs[m][off] = o0;
    *(us8*)&Qs[m][off + 8] = o1;
  }
  const ffrag fz = {0.f, 0.f, 0.f, 0.f};
  ffrag O[4] = {fz, fz, fz, fz};
  float lsum[4] = {0.f, 0.f, 0.f, 0.f};

  for (int n0 = 0; n0 < CHUNK; n0 += 128) {
    __syncthreads();
    {
      int n = tid >> 1, off = (tid & 1) * 32;
      const ush* src = &k_bf[((size_t)bh * SEQ + n_base + n0 + n) * HD + off];
#pragma unroll
      for (int u = 0; u < 4; ++u) *(us8*)&Ks[n][off + 8 * u] = *(const us8*)&src[8 * u];
    }
    {
      int d = tid >> 2, off = (tid & 3) * 32;
      const ush* src = &vT_bf[((size_t)bh * HD + d) * SEQ + n_base + n0 + off];
#pragma unroll
      for (int u = 0; u < 4; ++u) *(us8*)&Vs[d][off + 8 * u] = *(const us8*)&src[8 * u];
    }
    __syncthreads();
    ffrag S[8] = {fz, fz, fz, fz, fz, fz, fz, fz};
#pragma unroll
    for (int ks = 0; ks < 2; ++ks) {
      bfrag a = *(const bfrag*)&Qs[16 * w + lm][32 * ks + 8 * lq];
#pragma unroll
      for (int t = 0; t < 8; ++t) {
        bfrag b = *(const bfrag*)&Ks[16 * t + lm][32 * ks + 8 * lq];
        S[t] = __builtin_amdgcn_mfma_f32_16x16x32_bf16(a, b, S[t], 0, 0, 0);
      }
    }
#pragma unroll
    for (int t = 0; t < 8; ++t)
#pragma unroll
      for (int r = 0; r < 4; ++r) {
        float p = __expf(S[t][r]);
        lsum[r] += p;
        Ps[16 * w + 4 * lq + r][16 * t + lm] = f2bf(p);
      }
    __syncthreads();
#pragma unroll
    for (int kk = 0; kk < 4; ++kk) {
      bfrag a = *(const bfrag*)&Ps[16 * w + lm][32 * kk + 8 * lq];
#pragma unroll
      for (int t2 = 0; t2 < 4; ++t2) {
        bfrag b = *(const bfrag*)&Vs[16 * t2 + lm][32 * kk + 8 * lq];
        O[t2] = __builtin_amdgcn_mfma_f32_16x16x32_bf16(a, b, O[t2], 0, 0, 0);
      }
    }
  }
#pragma unroll
  for (int r = 0; r < 4; ++r) {
#pragma unroll
    for (int off = 1; off < 16; off <<= 1) lsum[r] += __shfl_xor(lsum[r], off);
  }
  const size_t pbase = (size_t)blockIdx.y * 32 + bh;
  if (lm == 0) {
#pragma unroll
    for (int r = 0; r < 4; ++r)
      l_part[pbase * NLM + m0 + 16 * w + 4 * lq + r] = lsum[r];
  }
#pragma unroll
  for (int t2 = 0; t2 < 4; ++t2)
#pragma unroll
    for (int r = 0; r < 4; ++r) {
      int m = m0 + 16 * w + 4 * lq + r;
      int d = 16 * t2 + lm;
      O_part[(pbase * NLM + m) * HD + d] = O[t2][r];
    }
}

// sim3_finalize: combine partials, write sv in B-form split ([d][m]).
// grid (8,32): blockIdx.x = {d-quarter (low 2 bits), m-half (bit 2)}.
__global__ __launch_bounds__(256) void sim3_finalize(const float* __restrict__ O_part,
                                                     const float* __restrict__ l_part,
                                                     ush* __restrict__ svBh,
                                                     ush* __restrict__ svBl) {
  __shared__ float T[128][17];
  __shared__ float ls[128];
  const int bh = blockIdx.y;
  const int d0 = (blockIdx.x & 3) * 16;
  const int m0 = (blockIdx.x >> 2) * 128;
  const int tid = threadIdx.x;
  if (tid < 128) {
    float s = 0.f;
#pragma unroll
    for (int c = 0; c < NCH; ++c) s += l_part[(size_t)(c * 32 + bh) * NLM + m0 + tid];
    ls[tid] = s;
  }
#pragma unroll
  for (int i = 0; i < 8; ++i) {
    int e = i * 256 + tid;          // [0, 2048)
    int m = e >> 4, dd = e & 15;
    float s = 0.f;
#pragma unroll
    for (int c = 0; c < NCH; ++c)
      s += O_part[(((size_t)(c * 32 + bh)) << 14) + (size_t)(m0 + m) * HD + d0 + dd];
    T[m][dd] = s;
  }
  __syncthreads();
#pragma unroll
  for (int i = 0; i < 8; ++i) {
    int e = i * 256 + tid;
    int dd = e >> 7, m = e & 127;
    float val = T[m][dd] / ls[m];
    ush h, l; splitf(val, h, l);
    size_t o = ((size_t)bh * HD + d0 + dd) * NLM + m0 + m;
    svBh[o] = h; svBl[o] = l;
  }
}

// ---------------------------------------------------------------------------
// K8: attn1 via MFMA: outp = softmax(q_bf @ klm^T) @ tt  (fp32 softmax)
// ---------------------------------------------------------------------------
__global__ __launch_bounds__(256) void attn1_mfma(const ush* __restrict__ q_bf,
                                                  const float* __restrict__ klm,
                                                  const ush* __restrict__ ttT,
                                                  float* __restrict__ outp) {
  __shared__ ush bufA[256 * 72];   // klm bf16 [256][72] then ttT [64][264]
  __shared__ ush bufB[64 * 264];   // qs [64][72] then Ps [64][264]
  const int bh = blockIdx.y;
  const int b = bh >> 3, h = bh & 7;
  const int i0 = blockIdx.x * 64;
  const int tid = threadIdx.x;
  const int w = tid >> 6, lane = tid & 63;
  const int lm = lane & 15, lq = lane >> 4;
  {
    int m = tid >> 2, off = (tid & 3) * 16;
    const ush* src = &q_bf[((size_t)bh * SEQ + i0 + m) * HD + off];
    *(us8*)&bufB[m * 72 + off] = *(const us8*)src;
    *(us8*)&bufB[m * 72 + off + 8] = *(const us8*)&src[8];
  }
  {
    const float* kb = klm + (size_t)bh * NLM * HD;
#pragma unroll
    for (int u = 0; u < 16; ++u) {
      int e4 = u * 256 + tid;
      float4 f = ((const float4*)kb)[e4];
      int row = e4 >> 4, col = (e4 & 15) * 4;
      ush* p = &bufA[row * 72 + col];
      p[0] = f2bf(f.x); p[1] = f2bf(f.y); p[2] = f2bf(f.z); p[3] = f2bf(f.w);
    }
  }
  __syncthreads();
  const ffrag fz = {0.f, 0.f, 0.f, 0.f};
  ffrag S[16];
#pragma unroll
  for (int t = 0; t < 16; ++t) S[t] = fz;
#pragma unroll
  for (int ks = 0; ks < 2; ++ks) {
    bfrag a = *(const bfrag*)&bufB[(16 * w + lm) * 72 + 32 * ks + 8 * lq];
#pragma unroll
    for (int t = 0; t < 16; ++t) {
      bfrag bb = *(const bfrag*)&bufA[(16 * t + lm) * 72 + 32 * ks + 8 * lq];
      S[t] = __builtin_amdgcn_mfma_f32_16x16x32_bf16(a, bb, S[t], 0, 0, 0);
    }
  }
  float rinv[4];
  float ev[16][4];
#pragma unroll
  for (int r = 0; r < 4; ++r) {
    float mx = -INFINITY;
#pragma unroll
    for (int t = 0; t < 16; ++t) mx = fmaxf(mx, S[t][r]);
#pragma unroll
    for (int off = 1; off < 16; off <<= 1) mx = fmaxf(mx, __shfl_xor(mx, off));
    float sm = 0.f;
#pragma unroll
    for (int t = 0; t < 16; ++t) { ev[t][r] = __expf(S[t][r] - mx); sm += ev[t][r]; }
#pragma unroll
    for (int off = 1; off < 16; off <<= 1) sm += __shfl_xor(sm, off);
    rinv[r] = 1.0f / sm;
  }
  __syncthreads();
#pragma unroll
  for (int t = 0; t < 16; ++t)
#pragma unroll
    for (int r = 0; r < 4; ++r)
      bufB[(16 * w + 4 * lq + r) * 264 + 16 * t + lm] = f2bf(ev[t][r]);
  {
    const ush* tb = ttT + (size_t)bh * HD * NLM;
#pragma unroll
    for (int u = 0; u < 8; ++u) {
      int e8 = u * 256 + tid;
      int row = e8 >> 5, col = (e8 & 31) * 8;
      *(us8*)&bufA[row * 264 + col] = *(const us8*)&tb[row * NLM + col];
    }
  }
  __syncthreads();
  ffrag O[4] = {fz, fz, fz, fz};
#pragma unroll
  for (int kk = 0; kk < 8; ++kk) {
    bfrag a = *(const bfrag*)&bufB[(16 * w + lm) * 264 + 32 * kk + 8 * lq];
#pragma unroll
    for (int t2 = 0; t2 < 4; ++t2) {
      bfrag bb = *(const bfrag*)&bufA[(16 * t2 + lm) * 264 + 32 * kk + 8 * lq];
      O[t2] = __builtin_amdgcn_mfma_f32_16x16x32_bf16(a, bb, O[t2], 0, 0, 0);
    }
  }
#pragma unroll
  for (int t2 = 0; t2 < 4; ++t2)
#pragma unroll
    for (int r = 0; r < 4; ++r) {
      int i = i0 + 16 * w + 4 * lq + r;
      int d = 16 * t2 + lm;
      outp[((size_t)b * SEQ + i) * DIMC + h * HD + d] = O[t2][r] * rinv[r];
    }
}

// ---------------------------------------------------------------------------
// K9: conv add + split: outp(fp32) + depthwise conv(vT) -> outph/outpl
// ---------------------------------------------------------------------------
__global__ __launch_bounds__(256) void conv_add_split(const float* __restrict__ outp,
                                                      const ush* __restrict__ vT,
                                                      const float* __restrict__ kern,
                                                      ush* __restrict__ oh,
                                                      ush* __restrict__ ol) {
  __shared__ float vt[64 * 97];   // [d][96+1], cols n0-16 .. n0+79
  __shared__ float ks[KWIN];
  const int bh = blockIdx.y;
  const int b = bh >> 3, hh = bh & 7;
  const int n0 = blockIdx.x * 64;
  const int tid = threadIdx.x;
  if (tid < KWIN) ks[tid] = kern[hh * KWIN + tid];
  for (int e = tid; e < 64 * 96; e += 256) {
    int d = e / 96, c = e % 96;
    int n = n0 - 16 + c;
    vt[d * 97 + c] = (n >= 0 && n < SEQ) ? bf2f(vT[((size_t)bh * HD + d) * SEQ + n]) : 0.f;
  }
  __syncthreads();
  const int d = tid & 63, g = tid >> 6;
  float wreg[48];
#pragma unroll
  for (int j = 0; j < 48; ++j) wreg[j] = vt[d * 97 + g * 16 + j];
#pragma unroll
  for (int nn = 0; nn < 16; ++nn) {
    float s = 0.f;
#pragma unroll
    for (int t = 0; t < KWIN; ++t) s = fmaf(ks[t], wreg[nn + t], s);
    int n = n0 + g * 16 + nn;
    size_t o = ((size_t)b * SEQ + n) * DIMC + hh * HD + d;
    float val = outp[o] + s;
    ush h, l; splitf(val, h, l);
    oh[o] = h; ol[o] = l;
  }
}

// ---------------------------------------------------------------------------
// K10: out = outp_split @ WoutT_split + bias — ROUND-5 LAYOUT (3-product:
// final projection is precision-critical, keep full split).
// BM=BN=128, grid (128, 4)
// ---------------------------------------------------------------------------
__global__ __launch_bounds__(256) void out_gemm_split(const ush* __restrict__ ah_g,
                                                      const ush* __restrict__ al_g,
                                                      const ush* __restrict__ bh_g,
                                                      const ush* __restrict__ bl_g,
                                                      const float* __restrict__ bias,
                                                      float* __restrict__ out) {
  __shared__ ush Ash[128][40], Asl[128][40];
  __shared__ ush Bsh[128][40], Bsl[128][40];
  const int tid = threadIdx.x;
  const int w = tid >> 6, lane = tid & 63;
  const int lm = lane & 15, lq = lane >> 4;
  const int wm = w >> 1, wn = w & 1;
  const int row0 = blockIdx.x * 128, col0 = blockIdx.y * 128;
  const ffrag fz = {0.f, 0.f, 0.f, 0.f};
  ffrag acc[4][4];
#pragma unroll
  for (int i = 0; i < 4; ++i)
#pragma unroll
    for (int j = 0; j < 4; ++j) acc[i][j] = fz;

  const int sm = tid >> 1, skoff = (tid & 1) * 16;
  for (int k0 = 0; k0 < 512; k0 += 32) {
    __syncthreads();
    {
      size_t ao = (size_t)(row0 + sm) * 512 + k0 + skoff;
      *(us8*)&Ash[sm][skoff]     = *(const us8*)&ah_g[ao];
      *(us8*)&Ash[sm][skoff + 8] = *(const us8*)&ah_g[ao + 8];
      *(us8*)&Asl[sm][skoff]     = *(const us8*)&al_g[ao];
      *(us8*)&Asl[sm][skoff + 8] = *(const us8*)&al_g[ao + 8];
      size_t bo = (size_t)(col0 + sm) * 512 + k0 + skoff;
      *(us8*)&Bsh[sm][skoff]     = *(const us8*)&bh_g[bo];
      *(us8*)&Bsh[sm][skoff + 8] = *(const us8*)&bh_g[bo + 8];
      *(us8*)&Bsl[sm][skoff]     = *(const us8*)&bl_g[bo];
      *(us8*)&Bsl[sm][skoff + 8] = *(const us8*)&bl_g[bo + 8];
    }
    __syncthreads();
    bfrag ah[4], al[4], bh[4], bl[4];
#pragma unroll
    for (int mt = 0; mt < 4; ++mt) {
      ah[mt] = *(const bfrag*)&Ash[64 * wm + 16 * mt + lm][8 * lq];
      al[mt] = *(const bfrag*)&Asl[64 * wm + 16 * mt + lm][8 * lq];
    }
#pragma unroll
    for (int nt = 0; nt < 4; ++nt) {
      bh[nt] = *(const bfrag*)&Bsh[64 * wn + 16 * nt + lm][8 * lq];
      bl[nt] = *(const bfrag*)&Bsl[64 * wn + 16 * nt + lm][8 * lq];
    }
#pragma unroll
    for (int mt = 0; mt < 4; ++mt)
#pragma unroll
      for (int nt = 0; nt < 4; ++nt) {
        acc[mt][nt] = __builtin_amdgcn_mfma_f32_16x16x32_bf16(ah[mt], bh[nt], acc[mt][nt], 0, 0, 0);
        acc[mt][nt] = __builtin_amdgcn_mfma_f32_16x16x32_bf16(al[mt], bh[nt], acc[mt][nt], 0, 0, 0);
        acc[mt][nt] = __builtin_amdgcn_mfma_f32_16x16x32_bf16(ah[mt], bl[nt], acc[mt][nt], 0, 0, 0);
      }
  }
#pragma unroll
  for (int mt = 0; mt < 4; ++mt)
#pragma unroll
    for (int nt = 0; nt < 4; ++nt) {
      int n = col0 + 64 * wn + 16 * nt + lm;
      float bv = bias[n];
#pragma unroll
      for (int r = 0; r < 4; ++r) {
        int m = row0 + 64 * wm + 16 * mt + 4 * lq + r;
        out[(size_t)m * 512 + n] = acc[mt][nt][r] + bv;
      }
    }
}

// ---------------------------------------------------------------------------
extern "C" void kernel_launch(void* const* d_in, const int* in_sizes, int n_in,
                              void* d_out, int out_size, void* d_ws, size_t ws_size,
                              hipStream_t stream) {
  const float* x    = (const float*)d_in[0];
  const float* Wqkv = (const float*)d_in[1];
  const float* Wout = (const float*)d_in[2];
  const float* bout = (const float*)d_in[3];
  const float* rker = (const float*)d_in[4];
  float* out = (float*)d_out;
  float* ws = (float*)d_ws;

  // workspace layout (float-element offsets), total ~186.6 MB
  ush*   vT     = (ush*)(ws);                          // 8388608 ush (v transposed)
  ush*   q_bf   = (ush*)(ws + 4194304);                // 8388608 ush
  float* regA   = ws + 8388608;                        // 8388608 f: k_bf -> outp
  float* regB   = ws + 16777216;                       // 8388608 f: xh+xl -> outph+outpl
  float* qlm    = ws + 25165824;                       // 524288
  float* klm    = ws + 25690112;                       // 524288
  float* regC   = ws + 26214400;                       // 2097152 f: t2(h,l) / ttT
  float* a2reg  = ws + 28311552;                       // 2097152 f: a2h+a2l
  float* zAreg  = ws + 30408704;                       // 4194304 f
  float* zBreg  = ws + 34603008;                       // 4194304 f
  float* xzreg  = ws + 38797312;                       // 4194304 f: Y + bar (later O_part/l_part)
  float* t3reg  = ws + 43515904;                       // 2097152 f: U (later svB)
  float* wqkvT  = ws + 45613056;                       // 786432 f
  float* woutT  = ws + 46399488;                       // 262144 f
  float* red    = ws + 46661632;                       // 128

  ush* k_bf  = (ush*)regA;
  float* outp = regA;
  ush* xh = (ush*)regB;                 // 8388608 ush
  ush* xl = (ush*)(regB + 4194304);     // 8388608 ush
  ush* outph = (ush*)regB;
  ush* outpl = (ush*)(regB + 4194304);
  ush* a2h = (ush*)a2reg;               // 2097152 ush each
  ush* a2l = (ush*)(a2reg + 1048576);
  ush* zA_[4] = {(ush*)zAreg, (ush*)(zAreg + 1048576), (ush*)(zAreg + 2097152), (ush*)(zAreg + 3145728)};
  ush* zB_[4] = {(ush*)zBreg, (ush*)(zBreg + 1048576), (ush*)(zBreg + 2097152), (ush*)(zBreg + 3145728)};
  ush* Y_h  = (ush*)xzreg;              // Y = a2@z, symmetric (row-major only)
  ush* Y_l  = (ush*)(xzreg + 1048576);
  unsigned* bar = (unsigned*)(xzreg + 2097152);  // 32 batches x 64 uints
  ush* t2_h = (ush*)regC;               // t2 = 7Y - Y^2, symmetric (row-major)
  ush* t2_l = (ush*)(regC + 1048576);
  ush* U_h  = (ush*)t3reg;              // U = z@Y (row-major)
  ush* U_l  = (ush*)(t3reg + 1048576);
  float* O_part = xzreg;                // after pinv
  float* l_part = xzreg + 2097152;
  ush* svB_h = (ush*)t3reg;             // after pinv
  ush* svB_l = (ush*)(t3reg + 262144);
  ush* ttT   = (ush*)regC;              // after pinv
  ush* wqkvT_h = (ush*)wqkvT;
  ush* wqkvT_l = (ush*)(wqkvT + 393216);
  ush* woutT_h = (ush*)woutT;
  ush* woutT_l = (ush*)(woutT + 131072);

  // --- pre-splits ---
  split_flat<<<2048, 256, 0, stream>>>(x, xh, xl, 2097152);
  transpose_split_w<<<dim3(48, 16), 256, 0, stream>>>(Wqkv, wqkvT_h, wqkvT_l, 512, 1536);
  transpose_split_w<<<dim3(16, 16), 256, 0, stream>>>(Wout, woutT_h, woutT_l, 512, 512);

  // --- qkv + landmarks (+ direct vT) ---
  qkv_mfma<<<dim3(128, 12), 256, 0, stream>>>(xh, xl, wqkvT_h,
                                              q_bf, k_bf, vT, qlm, klm);

  // --- attn2 + pinv init ---
  sim2_softmax<<<8192, 256, 0, stream>>>(qlm, klm, a2h, a2l);
  colmax<<<32, 256, 0, stream>>>(a2h, red);
  finalize_scale<<<1, 64, 0, stream>>>(red, bar);
  zinit_split<<<dim3(8, 8, 32), 256, 0, stream>>>(a2h, a2l, red,
                                                  zA_[0], zA_[1], zA_[2], zA_[3]);

  // --- pinv Newton-Schulz: entire 6-iter, 3-stage chain in ONE dispatch ---
  pinv_fused<<<512, 256, 0, stream>>>(
      a2h, a2l,
      zA_[0], zA_[1], zA_[2], zA_[3],
      zB_[0], zB_[1], zB_[2], zB_[3],
      Y_h, Y_l, t2_h, t2_l, U_h, U_l, bar);
  // final z (attn2_inv) lands in zA_ (full split)

  // --- sim3 (flash) ---
  sim3_mfma<<<dim3(4, NCH, 32), 256, 0, stream>>>(qlm, k_bf, vT, O_part, l_part);
  sim3_finalize<<<dim3(8, 32), 256, 0, stream>>>(O_part, l_part, svB_h, svB_l);

  // --- tt = attn2_inv @ sv (write ttT = tt^T plain bf16) ---
  bgemm_split<<<dim3(4, 1, 32), 256, 0, stream>>>(
      zA_[0], zA_[1], svB_h, svB_l,
      nullptr, nullptr, nullptr, nullptr,
      nullptr, nullptr, ttT, nullptr, 256, 64, 256, 0.f, 0.f, -1.f);

  // --- attn1 + conv + output projection ---
  attn1_mfma<<<dim3(64, 32), 256, 0, stream>>>(q_bf, klm, ttT, outp);
  conv_add_split<<<dim3(64, 32), 256, 0, stream>>>(outp, vT, rker, outph, outpl);
  out_gemm_split<<<dim3(128, 4), 256, 0, stream>>>(outph, outpl, woutT_h, woutT_l, bout, out);
}

// Round 5
// 1659.822 us; speedup vs baseline: 1.1476x; 1.1476x over previous
//
#include <hip/hip_runtime.h>
#include <math.h>

// Problem constants
constexpr int BATCH = 4;
constexpr int SEQ   = 4096;
constexpr int DIMC  = 512;
constexpr int NH    = 8;
constexpr int HD    = 64;
constexpr int NLM   = 256;   // landmarks M
constexpr int LWIN  = 16;    // SEQ / NLM
constexpr int KWIN  = 33;
constexpr int BH    = BATCH * NH; // 32

typedef __attribute__((ext_vector_type(8))) short  bfrag;  // 8 bf16 for MFMA A/B
typedef __attribute__((ext_vector_type(4))) float  ffrag;  // MFMA C/D
typedef __attribute__((ext_vector_type(8))) unsigned short us8;
typedef __attribute__((ext_vector_type(4))) unsigned short us4;
typedef unsigned short ush;

__device__ __forceinline__ ush f2bf(float f) {
  unsigned u = __builtin_bit_cast(unsigned, f);
  return (ush)((u + 0x7FFFu + ((u >> 16) & 1u)) >> 16);
}
__device__ __forceinline__ float bf2f(ush h) {
  unsigned u = ((unsigned)h) << 16;
  return __builtin_bit_cast(float, u);
}
__device__ __forceinline__ void splitf(float f, ush& h, ush& l) {
  h = f2bf(f);
  l = f2bf(f - bf2f(h));
}
// async global->LDS, 16B per lane: LDS dest = base + lane*16 (wave-uniform base)
__device__ __forceinline__ void gl_lds16(const ush* g, ush* l) {
  __builtin_amdgcn_global_load_lds(
      (const __attribute__((address_space(1))) void*)g,
      (__attribute__((address_space(3))) void*)l, 16, 0, 0);
}

// ---------------------------------------------------------------------------
// split_flat: fp32 -> (hi, lo) bf16, elementwise (x pre-split). Grid-stride.
// ---------------------------------------------------------------------------
__global__ void split_flat(const float* __restrict__ src, ush* __restrict__ oh,
                           ush* __restrict__ ol, int n4) {
  for (int i = blockIdx.x * 256 + threadIdx.x; i < n4; i += gridDim.x * 256) {
    float4 f = ((const float4*)src)[i];
    us4 h, l;
    float fs[4] = {f.x, f.y, f.z, f.w};
#pragma unroll
    for (int j = 0; j < 4; ++j) {
      ush hh, ll;
      splitf(fs[j], hh, ll);
      h[j] = hh; l[j] = ll;
    }
    ((us4*)oh)[i] = h;
    ((us4*)ol)[i] = l;
  }
}

// ---------------------------------------------------------------------------
// transpose_split_w: in [R][C] fp32 -> out [C][R] hi/lo bf16 (weights)
// ---------------------------------------------------------------------------
__global__ __launch_bounds__(256) void transpose_split_w(const float* __restrict__ in,
                                                         ush* __restrict__ oh,
                                                         ush* __restrict__ ol,
                                                         int R, int C) {
  __shared__ float T[32][33];
  const int tid = threadIdx.x;
  const int c0 = blockIdx.x * 32, r0 = blockIdx.y * 32;
#pragma unroll
  for (int u = 0; u < 4; ++u) {
    int r = (tid >> 5) * 4 + u, cl = tid & 31;
    T[r][cl] = in[(size_t)(r0 + r) * C + c0 + cl];
  }
  __syncthreads();
#pragma unroll
  for (int u = 0; u < 4; ++u) {
    int cl = (tid >> 5) * 4 + u, rl = tid & 31;
    float f = T[rl][cl];
    ush h, l; splitf(f, h, l);
    size_t o = (size_t)(c0 + cl) * R + r0 + rl;
    oh[o] = h; ol[o] = l;
  }
}

// ---------------------------------------------------------------------------
// K1: qkv MFMA GEMM — 2-product split (x split, W hi-only; dropped x_hi@W_lo
// term ~1.8e-3/elem == same order as bf16 output rounding; r4-verified,
// absmax unchanged). BM=BN=128, BK=32, 256 thr, LDS 30KB.
// Epilogue: q/k bf16 + landmark pooling; v written DIRECTLY TRANSPOSED.
// ---------------------------------------------------------------------------
__global__ __launch_bounds__(256) void qkv_mfma(const ush* __restrict__ xh,
                                                const ush* __restrict__ xl,
                                                const ush* __restrict__ wTh,
                                                ush* __restrict__ q_bf,
                                                ush* __restrict__ k_bf,
                                                ush* __restrict__ vT,
                                                float* __restrict__ qlm,
                                                float* __restrict__ klm) {
  __shared__ ush Ash[128][40], Asl[128][40];
  __shared__ ush Bsh[128][40];
  const int tid = threadIdx.x;
  const int w = tid >> 6, lane = tid & 63;
  const int lm = lane & 15, lq = lane >> 4;
  const int wm = w >> 1, wn = w & 1;
  const int row0 = blockIdx.x * 128, col0 = blockIdx.y * 128;
  const ffrag fz = {0.f, 0.f, 0.f, 0.f};
  ffrag acc[4][4];
#pragma unroll
  for (int i = 0; i < 4; ++i)
#pragma unroll
    for (int j = 0; j < 4; ++j) acc[i][j] = fz;

  const int sm = tid >> 1, skoff = (tid & 1) * 16;
  for (int k0 = 0; k0 < 512; k0 += 32) {
    __syncthreads();
    {
      size_t ao = (size_t)(row0 + sm) * 512 + k0 + skoff;
      *(us8*)&Ash[sm][skoff]     = *(const us8*)&xh[ao];
      *(us8*)&Ash[sm][skoff + 8] = *(const us8*)&xh[ao + 8];
      *(us8*)&Asl[sm][skoff]     = *(const us8*)&xl[ao];
      *(us8*)&Asl[sm][skoff + 8] = *(const us8*)&xl[ao + 8];
      size_t bo = (size_t)(col0 + sm) * 512 + k0 + skoff;
      *(us8*)&Bsh[sm][skoff]     = *(const us8*)&wTh[bo];
      *(us8*)&Bsh[sm][skoff + 8] = *(const us8*)&wTh[bo + 8];
    }
    __syncthreads();
    bfrag ah[4], al[4], bh[4];
#pragma unroll
    for (int mt = 0; mt < 4; ++mt) {
      ah[mt] = *(const bfrag*)&Ash[64 * wm + 16 * mt + lm][8 * lq];
      al[mt] = *(const bfrag*)&Asl[64 * wm + 16 * mt + lm][8 * lq];
    }
#pragma unroll
    for (int nt = 0; nt < 4; ++nt)
      bh[nt] = *(const bfrag*)&Bsh[64 * wn + 16 * nt + lm][8 * lq];
#pragma unroll
    for (int mt = 0; mt < 4; ++mt)
#pragma unroll
      for (int nt = 0; nt < 4; ++nt) {
        acc[mt][nt] = __builtin_amdgcn_mfma_f32_16x16x32_bf16(ah[mt], bh[nt], acc[mt][nt], 0, 0, 0);
        acc[mt][nt] = __builtin_amdgcn_mfma_f32_16x16x32_bf16(al[mt], bh[nt], acc[mt][nt], 0, 0, 0);
      }
  }
  // epilogue
#pragma unroll
  for (int mt = 0; mt < 4; ++mt) {
    int rbase = row0 + 64 * wm + 16 * mt;      // 16-aligned -> single window
    int b = rbase >> 12;
    int ntok_base = rbase & 4095;
    int win = ntok_base >> 4;
#pragma unroll
    for (int nt = 0; nt < 4; ++nt) {
      int n_local = 64 * wn + 16 * nt;          // frag col base (h uniform)
      int col = col0 + n_local + lm;
      int which = col >> 9;                     // 0=q 1=k 2=v
      int h = (col >> 6) & 7;
      int d = col & 63;
      int bh_i = b * NH + h;
      float scale = (which == 0) ? 0.125f : 1.0f;
      float vals[4];
      float s = 0.f;
#pragma unroll
      for (int r = 0; r < 4; ++r) {
        vals[r] = acc[mt][nt][r] * scale;
        s += vals[r];
      }
      if (which == 2) {
        // direct transposed store: vT[bh][d][ntok] (4 contiguous ntok/lane)
        ush* dst = &vT[((size_t)bh_i * HD + d) * SEQ + ntok_base + 4 * lq];
#pragma unroll
        for (int r = 0; r < 4; ++r) dst[r] = f2bf(vals[r]);
      } else {
        ush* dst = which == 0 ? q_bf : k_bf;
#pragma unroll
        for (int r = 0; r < 4; ++r) {
          int ntok = ntok_base + 4 * lq + r;
          dst[((size_t)bh_i * SEQ + ntok) * HD + d] = f2bf(vals[r]);
        }
        s += __shfl_xor(s, 16);
        s += __shfl_xor(s, 32);
        if (lq == 0) {
          float* lmdst = which == 0 ? qlm : klm;
          lmdst[((size_t)bh_i * NLM + win) * HD + d] = s * (1.0f / LWIN);
        }
      }
    }
  }
}

// ---------------------------------------------------------------------------
// K3: attn2 = softmax(qlm @ klm^T) rows -> split bf16 (a2h/a2l)
// ---------------------------------------------------------------------------
__global__ __launch_bounds__(256) void sim2_softmax(const float* __restrict__ qlm,
                                                    const float* __restrict__ klm,
                                                    ush* __restrict__ a2h,
                                                    ush* __restrict__ a2l) {
  int i = blockIdx.x & 255;
  int bh = blockIdx.x >> 8;
  int j = threadIdx.x;
  __shared__ float qrow[64];
  __shared__ float red[256];
  if (j < 64) qrow[j] = qlm[((size_t)bh * NLM + i) * HD + j];
  __syncthreads();
  const float* kr = klm + ((size_t)bh * NLM + j) * HD;
  float s = 0.f;
#pragma unroll
  for (int d = 0; d < 64; d += 4) {
    float4 kv = *(const float4*)&kr[d];
    s += qrow[d] * kv.x + qrow[d + 1] * kv.y + qrow[d + 2] * kv.z + qrow[d + 3] * kv.w;
  }
  red[j] = s; __syncthreads();
  for (int off = 128; off > 0; off >>= 1) {
    if (j < off) red[j] = fmaxf(red[j], red[j + off]);
    __syncthreads();
  }
  float mx = red[0]; __syncthreads();
  float e = expf(s - mx);
  red[j] = e; __syncthreads();
  for (int off = 128; off > 0; off >>= 1) {
    if (j < off) red[j] += red[j + off];
    __syncthreads();
  }
  float val = e / red[0];
  size_t o = ((size_t)bh * NLM + i) * NLM + j;
  ush h, l; splitf(val, h, l);
  a2h[o] = h; a2l[o] = l;
}

// ---------------------------------------------------------------------------
// K4a: per-bh column sums of attn2 (hi plane only), block max.
// attn2 rows are softmax rows -> row sums are exactly 1.
// ---------------------------------------------------------------------------
__global__ __launch_bounds__(256) void colmax(const ush* __restrict__ a2h,
                                              float* __restrict__ red) {
  int bh = blockIdx.x;
  int t = threadIdx.x;
  const size_t base = (size_t)bh * NLM * NLM;
  float cs = 0.f;
  for (int i = 0; i < NLM; ++i) cs += bf2f(a2h[base + (size_t)i * NLM + t]);
  __shared__ float r1[256];
  r1[t] = cs; __syncthreads();
  for (int off = 128; off > 0; off >>= 1) {
    if (t < off) r1[t] = fmaxf(r1[t], r1[t + off]);
    __syncthreads();
  }
  if (t == 0) red[bh] = r1[0];
}

// finalize_scale: also zero-initializes the pinv_fused barrier flags
// (re-zeroed every launch -> graph/replay safe).
__global__ void finalize_scale(float* __restrict__ red, unsigned* __restrict__ bar) {
  int t = threadIdx.x;
  for (int i = t; i < 2048; i += 64) bar[i] = 0u;
  if (t == 0) {
    float m1 = -1e30f;
    for (int i = 0; i < BH; ++i) m1 = fmaxf(m1, red[i]);
    red[64] = 1.0f / m1;   // row-sum max == 1 exactly (softmax rows)
  }
}

// ---------------------------------------------------------------------------
// K4c: z0 = attn2^T * invscale, A-form + B-form splits
// ---------------------------------------------------------------------------
__global__ __launch_bounds__(256) void zinit_split(const ush* __restrict__ a2h,
                                                   const ush* __restrict__ a2l,
                                                   const float* __restrict__ red,
                                                   ush* __restrict__ zAh, ush* __restrict__ zAl,
                                                   ush* __restrict__ zBh, ush* __restrict__ zBl) {
  __shared__ float T[32][33];
  const int tid = threadIdx.x;
  const int bh = blockIdx.z;
  const int j0 = blockIdx.x * 32, i0 = blockIdx.y * 32;
  const float s = red[64];
  const size_t base = (size_t)bh * NLM * NLM;
#pragma unroll
  for (int u = 0; u < 4; ++u) {
    int jl = (tid >> 5) * 4 + u, il = tid & 31;
    size_t o = base + (size_t)(j0 + jl) * NLM + i0 + il;
    float a = (bf2f(a2h[o]) + bf2f(a2l[o])) * s;
    T[jl][il] = a;
    ush h, l; splitf(a, h, l);
    zBh[o] = h; zBl[o] = l;   // zB[j][i] = a2[j][i]*s
  }
  __syncthreads();
#pragma unroll
  for (int u = 0; u < 4; ++u) {
    int il = (tid >> 5) * 4 + u, jl = tid & 31;
    float a = T[jl][il];
    ush h, l; splitf(a, h, l);
    size_t o = base + (size_t)(i0 + il) * NLM + j0 + jl;  // zA[i][j] = a2[j][i]*s
    zAh[o] = h; zAl[o] = l;
  }
}

// ---------------------------------------------------------------------------
// K5 core: one 64x64 tile of C = A@B^T(stored) with split-bf16 planes.
// m97 structure: global_load_lds staging, BK=64. Null lo-pointers skip planes.
// Epilogue: y = coef * (alpha*E1 + beta*E2 - C); outputs row-major (oA) and/or
// transposed B-form (oB). FORCEINLINE ONLY (noinline variant corrupted the
// global_load_lds destination path -> round-2 NaN).
// ---------------------------------------------------------------------------
__device__ __forceinline__ void stage_gemm(
    ush (*S)[2][8][64][8],   // LDS [2][2][8][64][8] = 32 KB
    const ush* Ah, const ush* Al, const ush* Bh, const ush* Bl,
    const ush* E1h, const ush* E1l, const ush* E2h, const ush* E2l,
    ush* oAh, ush* oAl, ush* oBh, ush* oBl,
    int M, int N, int K, float alpha, float beta, float coef,
    int bx, int by, int batch, int tid) {
  const size_t abase = (size_t)batch * M * K;
  const size_t bbase = (size_t)batch * N * K;
  const size_t ebase = (size_t)batch * M * N;
  const int w = tid >> 6, lane = tid & 63;
  const int lm = lane & 15, lq = lane >> 4;
  const int wm = w >> 1, wn = w & 1;
  const int row0 = bx * 64, col0 = by * 64;
  const bool uAl = (Al != nullptr);
  const bool uBl = (Bl != nullptr);
  const ffrag fz = {0.f, 0.f, 0.f, 0.f};
  ffrag acc[2][2] = {{fz, fz}, {fz, fz}};

  const size_t arow = abase + (size_t)(row0 + lane) * K;   // per-lane
  const size_t brow = bbase + (size_t)(col0 + lane) * K;

  for (int k0 = 0; k0 < K; k0 += 64) {
    __syncthreads();
    // wave w stages k-chunks {2w, 2w+1} for A and B (lo planes only if used)
#pragma unroll
    for (int ci = 0; ci < 2; ++ci) {
      int c = 2 * w + ci;
      gl_lds16(&Ah[arow + k0 + 8 * c], &S[0][0][c][0][0]);
      gl_lds16(&Bh[brow + k0 + 8 * c], &S[1][0][c][0][0]);
      if (uAl) gl_lds16(&Al[arow + k0 + 8 * c], &S[0][1][c][0][0]);
      if (uBl) gl_lds16(&Bl[brow + k0 + 8 * c], &S[1][1][c][0][0]);
    }
    __syncthreads();   // compiler emits vmcnt(0) drain here (m97 structure)
#pragma unroll
    for (int ks = 0; ks < 2; ++ks) {
      bfrag ah[2], al[2], bhf[2], blf[2];
#pragma unroll
      for (int mt = 0; mt < 2; ++mt) {
        ah[mt] = *(const bfrag*)&S[0][0][4 * ks + lq][32 * wm + 16 * mt + lm][0];
        if (uAl) al[mt] = *(const bfrag*)&S[0][1][4 * ks + lq][32 * wm + 16 * mt + lm][0];
      }
#pragma unroll
      for (int nt = 0; nt < 2; ++nt) {
        bhf[nt] = *(const bfrag*)&S[1][0][4 * ks + lq][32 * wn + 16 * nt + lm][0];
        if (uBl) blf[nt] = *(const bfrag*)&S[1][1][4 * ks + lq][32 * wn + 16 * nt + lm][0];
      }
#pragma unroll
      for (int mt = 0; mt < 2; ++mt)
#pragma unroll
        for (int nt = 0; nt < 2; ++nt) {
          acc[mt][nt] = __builtin_amdgcn_mfma_f32_16x16x32_bf16(ah[mt], bhf[nt], acc[mt][nt], 0, 0, 0);
          if (uAl) acc[mt][nt] = __builtin_amdgcn_mfma_f32_16x16x32_bf16(al[mt], bhf[nt], acc[mt][nt], 0, 0, 0);
          if (uBl) acc[mt][nt] = __builtin_amdgcn_mfma_f32_16x16x32_bf16(ah[mt], blf[nt], acc[mt][nt], 0, 0, 0);
        }
    }
  }
#pragma unroll
  for (int mt = 0; mt < 2; ++mt)
#pragma unroll
    for (int nt = 0; nt < 2; ++nt) {
      int n = col0 + 32 * wn + 16 * nt + lm;
#pragma unroll
      for (int r = 0; r < 4; ++r) {
        int m = row0 + 32 * wm + 16 * mt + 4 * lq + r;
        float c = acc[mt][nt][r];
        float e = 0.f;
        size_t eo = ebase + (size_t)m * N + n;
        if (E1h) {
          float t = bf2f(E1h[eo]);
          if (E1l) t += bf2f(E1l[eo]);
          e += alpha * t;
        }
        if (E2h) {
          float t = bf2f(E2h[eo]);
          if (E2l) t += bf2f(E2l[eo]);
          e += beta * t;
        }
        float y = coef * (e - c);
        ush h, l; splitf(y, h, l);
        if (oAh) {
          size_t o = ebase + (size_t)m * N + n;
          oAh[o] = h;
          if (oAl) oAl[o] = l;
        }
        if (oBh) {
          size_t o = (size_t)batch * N * M + (size_t)n * M + m;
          oBh[o] = h;
          if (oBl) oBl[o] = l;
        }
      }
    }
}

__global__ __launch_bounds__(256) void bgemm_split(
    const ush* Ah, const ush* Al, const ush* Bh, const ush* Bl,
    const ush* E1h, const ush* E1l, const ush* E2h, const ush* E2l,
    ush* oAh, ush* oAl, ush* oBh, ush* oBl,
    int M, int N, int K, float alpha, float beta, float coef) {
  __shared__ ush S[2][2][8][64][8];
  stage_gemm(S, Ah, Al, Bh, Bl, E1h, E1l, E2h, E2l, oAh, oAl, oBh, oBl,
             M, N, K, alpha, beta, coef, blockIdx.x, blockIdx.y, blockIdx.z,
             threadIdx.x);
}

// ---------------------------------------------------------------------------
// Per-batch 16-block barrier for pinv_fused — ROUND-5 FIX.
// AGENT (device) scope: writeback/invalidate stops at the coherent LLC, not
// DRAM. RELAXED polling + ONE acquire fence after the wait: round-4's
// ACQUIRE-in-poll invalidated L2 every poll iteration from ~480 blocks ->
// 600 MB HBM traffic, 1.5 ms. Atomic ops at agent scope read/modify at the
// coherent point (m20: device-scope atomics are cross-XCD sound), so relaxed
// polls observe the gen bump; the trailing fence orders the data reads.
// ---------------------------------------------------------------------------
__device__ __forceinline__ void gbar16(unsigned* cnt, unsigned* gen) {
  __syncthreads();
  if (threadIdx.x == 0) {
    unsigned g = __hip_atomic_load(gen, __ATOMIC_RELAXED, __HIP_MEMORY_SCOPE_AGENT);
    __threadfence();   // release: stage stores written back to coherent point
    unsigned old = __hip_atomic_fetch_add(cnt, 1u, __ATOMIC_ACQ_REL, __HIP_MEMORY_SCOPE_AGENT);
    if (old == 15u) {
      __hip_atomic_store(cnt, 0u, __ATOMIC_RELAXED, __HIP_MEMORY_SCOPE_AGENT);
      __hip_atomic_fetch_add(gen, 1u, __ATOMIC_RELEASE, __HIP_MEMORY_SCOPE_AGENT);
    } else {
      while (__hip_atomic_load(gen, __ATOMIC_RELAXED, __HIP_MEMORY_SCOPE_AGENT) == g)
        __builtin_amdgcn_s_sleep(8);
    }
    __threadfence();   // acquire: one L2 invalidate before reading peers' data
  }
  __syncthreads();
}

// ---------------------------------------------------------------------------
// pinv_fused: entire 6-iteration, 3-stage Newton-Schulz chain in ONE dispatch.
// Grid = 512 (bx 0..3, by 0..3, bz 0..31); LB(256,2) + 32 KB LDS -> 2
// blocks/CU, all co-resident (r4: verified, occupancy 24.5%). Per-batch
// dependencies -> 16-block barriers; 32 chains drift independently.
//   S1: Y = a2@z              (Y symmetric: row-major only)
//   S2: t2 = 7Y - Y@Y ; U = z@Y   (each block does both tiles)
//   S3: z' = 0.25*(13z - 15U + U@t2)  (A-form + B-form)
// iters 0-3 plain bf16, iter 4 split-arith, iter 5 full split.
// r4 verified CORRECT (absmax bit-identical); r5 fixes only the fence cost.
// ---------------------------------------------------------------------------
__global__ __launch_bounds__(256, 2) void pinv_fused(
    const ush* a2h, const ush* a2l,
    ush* zA0, ush* zA1, ush* zA2, ush* zA3,
    ush* zB0, ush* zB1, ush* zB2, ush* zB3,
    ush* Y_h, ush* Y_l, ush* t2_h, ush* t2_l, ush* U_h, ush* U_l,
    unsigned* bar) {
  __shared__ ush S[2][2][8][64][8];
  const int tid = threadIdx.x;
  const int b = blockIdx.x;
  const int bx = b & 3, by = (b >> 2) & 3, bz = b >> 4;
  unsigned* cnt = bar + bz * 64;
  unsigned* gen = cnt + 32;

  ush* zc0 = zA0; ush* zc1 = zA1; ush* zc2 = zA2; ush* zc3 = zA3;
  ush* zn0 = zB0; ush* zn1 = zB1; ush* zn2 = zB2; ush* zn3 = zB3;

#pragma unroll 1
  for (int it = 0; it < 6; ++it) {
    const bool zin_s  = (it == 5);   // z input has a valid lo plane
    const bool a2_s   = (it >= 4);   // use a2 lo plane
    const bool mid_s  = (it >= 4);   // Y/t2/U intermediates split
    const bool zout_s = (it >= 4);   // write z split
    // S1: Y = a2 @ z
    stage_gemm(S, a2h, a2_s ? a2l : nullptr, zc2, zin_s ? zc3 : nullptr,
               nullptr, nullptr, nullptr, nullptr,
               Y_h, mid_s ? Y_l : nullptr, nullptr, nullptr,
               256, 256, 256, 0.f, 0.f, -1.f, bx, by, bz, tid);
    gbar16(cnt, gen);
    // S2a: t2 = 7Y - Y@Y  (Y symmetric -> row-major serves as B)
    stage_gemm(S, Y_h, mid_s ? Y_l : nullptr, Y_h, mid_s ? Y_l : nullptr,
               Y_h, mid_s ? Y_l : nullptr, nullptr, nullptr,
               t2_h, mid_s ? t2_l : nullptr, nullptr, nullptr,
               256, 256, 256, 7.f, 0.f, 1.f, bx, by, bz, tid);
    // S2b: U = z @ Y
    stage_gemm(S, zc0, zin_s ? zc1 : nullptr, Y_h, mid_s ? Y_l : nullptr,
               nullptr, nullptr, nullptr, nullptr,
               U_h, mid_s ? U_l : nullptr, nullptr, nullptr,
               256, 256, 256, 0.f, 0.f, -1.f, bx, by, bz, tid);
    gbar16(cnt, gen);
    // S3: z' = 0.25*(13 z - 15 U + U@t2)
    stage_gemm(S, U_h, mid_s ? U_l : nullptr, t2_h, mid_s ? t2_l : nullptr,
               zc0, zin_s ? zc1 : nullptr,      // E1 = z  (alpha = -13)
               U_h, mid_s ? U_l : nullptr,      // E2 = U  (beta  = +15)
               zn0, zout_s ? zn1 : nullptr, zn2, zout_s ? zn3 : nullptr,
               256, 256, 256, -13.f, 15.f, -0.25f, bx, by, bz, tid);
    if (it < 5) gbar16(cnt, gen);
    ush* t;
    t = zc0; zc0 = zn0; zn0 = t;
    t = zc1; zc1 = zn1; zn1 = t;
    t = zc2; zc2 = zn2; zn2 = t;
    t = zc3; zc3 = zn3; zn3 = t;
  }
  // final z (attn2_inv) lands in the zA set (6 swaps).
}

// ---------------------------------------------------------------------------
// K6: sim3 flash via MFMA, no max-subtraction (scores tiny). n-split NCH ways.
// ---------------------------------------------------------------------------
constexpr int NCH = 4;
__global__ __launch_bounds__(256) void sim3_mfma(const float* __restrict__ qlm,
                                                 const ush* __restrict__ k_bf,
                                                 const ush* __restrict__ vT_bf,
                                                 float* __restrict__ O_part,
                                                 float* __restrict__ l_part) {
  constexpr int CHUNK = SEQ / NCH;  // 1024
  __shared__ ush Qs[64][72];
  __shared__ ush Ks[128][72];
  __shared__ ush Vs[64][136];
  __shared__ ush Ps[64][136];
  const int bh = blockIdx.z;
  const int m0 = blockIdx.x * 64;
  const int n_base = blockIdx.y * CHUNK;
  const int tid = threadIdx.x;
  const int w = tid >> 6, lane = tid & 63;
  const int lm = lane & 15, lq = lane >> 4;
  {
    int m = tid >> 2, off = (tid & 3) * 16;
    const float* src = &qlm[((size_t)bh * NLM + m0 + m) * HD + off];
    us8 o0, o1;
#pragma unroll
    for (int j = 0; j < 8; ++j) o0[j] = f2bf(src[j]);
#pragma unroll
    for (int j = 0; j < 8; ++j) o1[j] = f2bf(src[8 + j]);
    *(us8*)&Qs[m][off] = o0;
    *(us8*)&Qs[m][off + 8] = o1;
  }
  const ffrag fz = {0.f, 0.f, 0.f, 0.f};
  ffrag O[4] = {fz, fz, fz, fz};
  float lsum[4] = {0.f, 0.f, 0.f, 0.f};

  for (int n0 = 0; n0 < CHUNK; n0 += 128) {
    __syncthreads();
    {
      int n = tid >> 1, off = (tid & 1) * 32;
      const ush* src = &k_bf[((size_t)bh * SEQ + n_base + n0 + n) * HD + off];
#pragma unroll
      for (int u = 0; u < 4; ++u) *(us8*)&Ks[n][off + 8 * u] = *(const us8*)&src[8 * u];
    }
    {
      int d = tid >> 2, off = (tid & 3) * 32;
      const ush* src = &vT_bf[((size_t)bh * HD + d) * SEQ + n_base + n0 + off];
#pragma unroll
      for (int u = 0; u < 4; ++u) *(us8*)&Vs[d][off + 8 * u] = *(const us8*)&src[8 * u];
    }
    __syncthreads();
    ffrag S[8] = {fz, fz, fz, fz, fz, fz, fz, fz};
#pragma unroll
    for (int ks = 0; ks < 2; ++ks) {
      bfrag a = *(const bfrag*)&Qs[16 * w + lm][32 * ks + 8 * lq];
#pragma unroll
      for (int t = 0; t < 8; ++t) {
        bfrag b = *(const bfrag*)&Ks[16 * t + lm][32 * ks + 8 * lq];
        S[t] = __builtin_amdgcn_mfma_f32_16x16x32_bf16(a, b, S[t], 0, 0, 0);
      }
    }
#pragma unroll
    for (int t = 0; t < 8; ++t)
#pragma unroll
      for (int r = 0; r < 4; ++r) {
        float p = __expf(S[t][r]);
        lsum[r] += p;
        Ps[16 * w + 4 * lq + r][16 * t + lm] = f2bf(p);
      }
    __syncthreads();
#pragma unroll
    for (int kk = 0; kk < 4; ++kk) {
      bfrag a = *(const bfrag*)&Ps[16 * w + lm][32 * kk + 8 * lq];
#pragma unroll
      for (int t2 = 0; t2 < 4; ++t2) {
        bfrag b = *(const bfrag*)&Vs[16 * t2 + lm][32 * kk + 8 * lq];
        O[t2] = __builtin_amdgcn_mfma_f32_16x16x32_bf16(a, b, O[t2], 0, 0, 0);
      }
    }
  }
#pragma unroll
  for (int r = 0; r < 4; ++r) {
#pragma unroll
    for (int off = 1; off < 16; off <<= 1) lsum[r] += __shfl_xor(lsum[r], off);
  }
  const size_t pbase = (size_t)blockIdx.y * 32 + bh;
  if (lm == 0) {
#pragma unroll
    for (int r = 0; r < 4; ++r)
      l_part[pbase * NLM + m0 + 16 * w + 4 * lq + r] = lsum[r];
  }
#pragma unroll
  for (int t2 = 0; t2 < 4; ++t2)
#pragma unroll
    for (int r = 0; r < 4; ++r) {
      int m = m0 + 16 * w + 4 * lq + r;
      int d = 16 * t2 + lm;
      O_part[(pbase * NLM + m) * HD + d] = O[t2][r];
    }
}

// sim3_finalize: combine partials, write sv in B-form split ([d][m]).
// grid (8,32): blockIdx.x = {d-quarter (low 2 bits), m-half (bit 2)}.
__global__ __launch_bounds__(256) void sim3_finalize(const float* __restrict__ O_part,
                                                     const float* __restrict__ l_part,
                                                     ush* __restrict__ svBh,
                                                     ush* __restrict__ svBl) {
  __shared__ float T[128][17];
  __shared__ float ls[128];
  const int bh = blockIdx.y;
  const int d0 = (blockIdx.x & 3) * 16;
  const int m0 = (blockIdx.x >> 2) * 128;
  const int tid = threadIdx.x;
  if (tid < 128) {
    float s = 0.f;
#pragma unroll
    for (int c = 0; c < NCH; ++c) s += l_part[(size_t)(c * 32 + bh) * NLM + m0 + tid];
    ls[tid] = s;
  }
#pragma unroll
  for (int i = 0; i < 8; ++i) {
    int e = i * 256 + tid;          // [0, 2048)
    int m = e >> 4, dd = e & 15;
    float s = 0.f;
#pragma unroll
    for (int c = 0; c < NCH; ++c)
      s += O_part[(((size_t)(c * 32 + bh)) << 14) + (size_t)(m0 + m) * HD + d0 + dd];
    T[m][dd] = s;
  }
  __syncthreads();
#pragma unroll
  for (int i = 0; i < 8; ++i) {
    int e = i * 256 + tid;
    int dd = e >> 7, m = e & 127;
    float val = T[m][dd] / ls[m];
    ush h, l; splitf(val, h, l);
    size_t o = ((size_t)bh * HD + d0 + dd) * NLM + m0 + m;
    svBh[o] = h; svBl[o] = l;
  }
}

// ---------------------------------------------------------------------------
// K8: attn1 via MFMA: outp = softmax(q_bf @ klm^T) @ tt  (fp32 softmax)
// ---------------------------------------------------------------------------
__global__ __launch_bounds__(256) void attn1_mfma(const ush* __restrict__ q_bf,
                                                  const float* __restrict__ klm,
                                                  const ush* __restrict__ ttT,
                                                  float* __restrict__ outp) {
  __shared__ ush bufA[256 * 72];   // klm bf16 [256][72] then ttT [64][264]
  __shared__ ush bufB[64 * 264];   // qs [64][72] then Ps [64][264]
  const int bh = blockIdx.y;
  const int b = bh >> 3, h = bh & 7;
  const int i0 = blockIdx.x * 64;
  const int tid = threadIdx.x;
  const int w = tid >> 6, lane = tid & 63;
  const int lm = lane & 15, lq = lane >> 4;
  {
    int m = tid >> 2, off = (tid & 3) * 16;
    const ush* src = &q_bf[((size_t)bh * SEQ + i0 + m) * HD + off];
    *(us8*)&bufB[m * 72 + off] = *(const us8*)src;
    *(us8*)&bufB[m * 72 + off + 8] = *(const us8*)&src[8];
  }
  {
    const float* kb = klm + (size_t)bh * NLM * HD;
#pragma unroll
    for (int u = 0; u < 16; ++u) {
      int e4 = u * 256 + tid;
      float4 f = ((const float4*)kb)[e4];
      int row = e4 >> 4, col = (e4 & 15) * 4;
      ush* p = &bufA[row * 72 + col];
      p[0] = f2bf(f.x); p[1] = f2bf(f.y); p[2] = f2bf(f.z); p[3] = f2bf(f.w);
    }
  }
  __syncthreads();
  const ffrag fz = {0.f, 0.f, 0.f, 0.f};
  ffrag S[16];
#pragma unroll
  for (int t = 0; t < 16; ++t) S[t] = fz;
#pragma unroll
  for (int ks = 0; ks < 2; ++ks) {
    bfrag a = *(const bfrag*)&bufB[(16 * w + lm) * 72 + 32 * ks + 8 * lq];
#pragma unroll
    for (int t = 0; t < 16; ++t) {
      bfrag bb = *(const bfrag*)&bufA[(16 * t + lm) * 72 + 32 * ks + 8 * lq];
      S[t] = __builtin_amdgcn_mfma_f32_16x16x32_bf16(a, bb, S[t], 0, 0, 0);
    }
  }
  float rinv[4];
  float ev[16][4];
#pragma unroll
  for (int r = 0; r < 4; ++r) {
    float mx = -INFINITY;
#pragma unroll
    for (int t = 0; t < 16; ++t) mx = fmaxf(mx, S[t][r]);
#pragma unroll
    for (int off = 1; off < 16; off <<= 1) mx = fmaxf(mx, __shfl_xor(mx, off));
    float sm = 0.f;
#pragma unroll
    for (int t = 0; t < 16; ++t) { ev[t][r] = __expf(S[t][r] - mx); sm += ev[t][r]; }
#pragma unroll
    for (int off = 1; off < 16; off <<= 1) sm += __shfl_xor(sm, off);
    rinv[r] = 1.0f / sm;
  }
  __syncthreads();
#pragma unroll
  for (int t = 0; t < 16; ++t)
#pragma unroll
    for (int r = 0; r < 4; ++r)
      bufB[(16 * w + 4 * lq + r) * 264 + 16 * t + lm] = f2bf(ev[t][r]);
  {
    const ush* tb = ttT + (size_t)bh * HD * NLM;
#pragma unroll
    for (int u = 0; u < 8; ++u) {
      int e8 = u * 256 + tid;
      int row = e8 >> 5, col = (e8 & 31) * 8;
      *(us8*)&bufA[row * 264 + col] = *(const us8*)&tb[row * NLM + col];
    }
  }
  __syncthreads();
  ffrag O[4] = {fz, fz, fz, fz};
#pragma unroll
  for (int kk = 0; kk < 8; ++kk) {
    bfrag a = *(const bfrag*)&bufB[(16 * w + lm) * 264 + 32 * kk + 8 * lq];
#pragma unroll
    for (int t2 = 0; t2 < 4; ++t2) {
      bfrag bb = *(const bfrag*)&bufA[(16 * t2 + lm) * 264 + 32 * kk + 8 * lq];
      O[t2] = __builtin_amdgcn_mfma_f32_16x16x32_bf16(a, bb, O[t2], 0, 0, 0);
    }
  }
#pragma unroll
  for (int t2 = 0; t2 < 4; ++t2)
#pragma unroll
    for (int r = 0; r < 4; ++r) {
      int i = i0 + 16 * w + 4 * lq + r;
      int d = 16 * t2 + lm;
      outp[((size_t)b * SEQ + i) * DIMC + h * HD + d] = O[t2][r] * rinv[r];
    }
}

// ---------------------------------------------------------------------------
// K9: conv add + split: outp(fp32) + depthwise conv(vT) -> outph/outpl
// ---------------------------------------------------------------------------
__global__ __launch_bounds__(256) void conv_add_split(const float* __restrict__ outp,
                                                      const ush* __restrict__ vT,
                                                      const float* __restrict__ kern,
                                                      ush* __restrict__ oh,
                                                      ush* __restrict__ ol) {
  __shared__ float vt[64 * 97];   // [d][96+1], cols n0-16 .. n0+79
  __shared__ float ks[KWIN];
  const int bh = blockIdx.y;
  const int b = bh >> 3, hh = bh & 7;
  const int n0 = blockIdx.x * 64;
  const int tid = threadIdx.x;
  if (tid < KWIN) ks[tid] = kern[hh * KWIN + tid];
  for (int e = tid; e < 64 * 96; e += 256) {
    int d = e / 96, c = e % 96;
    int n = n0 - 16 + c;
    vt[d * 97 + c] = (n >= 0 && n < SEQ) ? bf2f(vT[((size_t)bh * HD + d) * SEQ + n]) : 0.f;
  }
  __syncthreads();
  const int d = tid & 63, g = tid >> 6;
  float wreg[48];
#pragma unroll
  for (int j = 0; j < 48; ++j) wreg[j] = vt[d * 97 + g * 16 + j];
#pragma unroll
  for (int nn = 0; nn < 16; ++nn) {
    float s = 0.f;
#pragma unroll
    for (int t = 0; t < KWIN; ++t) s = fmaf(ks[t], wreg[nn + t], s);
    int n = n0 + g * 16 + nn;
    size_t o = ((size_t)b * SEQ + n) * DIMC + hh * HD + d;
    float val = outp[o] + s;
    ush h, l; splitf(val, h, l);
    oh[o] = h; ol[o] = l;
  }
}

// ---------------------------------------------------------------------------
// K10: out = outp_split @ WoutT_split + bias — ROUND-5 LAYOUT (3-product:
// final projection is precision-critical, keep full split).
// BM=BN=128, grid (128, 4)
// ---------------------------------------------------------------------------
__global__ __launch_bounds__(256) void out_gemm_split(const ush* __restrict__ ah_g,
                                                      const ush* __restrict__ al_g,
                                                      const ush* __restrict__ bh_g,
                                                      const ush* __restrict__ bl_g,
                                                      const float* __restrict__ bias,
                                                      float* __restrict__ out) {
  __shared__ ush Ash[128][40], Asl[128][40];
  __shared__ ush Bsh[128][40], Bsl[128][40];
  const int tid = threadIdx.x;
  const int w = tid >> 6, lane = tid & 63;
  const int lm = lane & 15, lq = lane >> 4;
  const int wm = w >> 1, wn = w & 1;
  const int row0 = blockIdx.x * 128, col0 = blockIdx.y * 128;
  const ffrag fz = {0.f, 0.f, 0.f, 0.f};
  ffrag acc[4][4];
#pragma unroll
  for (int i = 0; i < 4; ++i)
#pragma unroll
    for (int j = 0; j < 4; ++j) acc[i][j] = fz;

  const int sm = tid >> 1, skoff = (tid & 1) * 16;
  for (int k0 = 0; k0 < 512; k0 += 32) {
    __syncthreads();
    {
      size_t ao = (size_t)(row0 + sm) * 512 + k0 + skoff;
      *(us8*)&Ash[sm][skoff]     = *(const us8*)&ah_g[ao];
      *(us8*)&Ash[sm][skoff + 8] = *(const us8*)&ah_g[ao + 8];
      *(us8*)&Asl[sm][skoff]     = *(const us8*)&al_g[ao];
      *(us8*)&Asl[sm][skoff + 8] = *(const us8*)&al_g[ao + 8];
      size_t bo = (size_t)(col0 + sm) * 512 + k0 + skoff;
      *(us8*)&Bsh[sm][skoff]     = *(const us8*)&bh_g[bo];
      *(us8*)&Bsh[sm][skoff + 8] = *(const us8*)&bh_g[bo + 8];
      *(us8*)&Bsl[sm][skoff]     = *(const us8*)&bl_g[bo];
      *(us8*)&Bsl[sm][skoff + 8] = *(const us8*)&bl_g[bo + 8];
    }
    __syncthreads();
    bfrag ah[4], al[4], bh[4], bl[4];
#pragma unroll
    for (int mt = 0; mt < 4; ++mt) {
      ah[mt] = *(const bfrag*)&Ash[64 * wm + 16 * mt + lm][8 * lq];
      al[mt] = *(const bfrag*)&Asl[64 * wm + 16 * mt + lm][8 * lq];
    }
#pragma unroll
    for (int nt = 0; nt < 4; ++nt) {
      bh[nt] = *(const bfrag*)&Bsh[64 * wn + 16 * nt + lm][8 * lq];
      bl[nt] = *(const bfrag*)&Bsl[64 * wn + 16 * nt + lm][8 * lq];
    }
#pragma unroll
    for (int mt = 0; mt < 4; ++mt)
#pragma unroll
      for (int nt = 0; nt < 4; ++nt) {
        acc[mt][nt] = __builtin_amdgcn_mfma_f32_16x16x32_bf16(ah[mt], bh[nt], acc[mt][nt], 0, 0, 0);
        acc[mt][nt] = __builtin_amdgcn_mfma_f32_16x16x32_bf16(al[mt], bh[nt], acc[mt][nt], 0, 0, 0);
        acc[mt][nt] = __builtin_amdgcn_mfma_f32_16x16x32_bf16(ah[mt], bl[nt], acc[mt][nt], 0, 0, 0);
      }
  }
#pragma unroll
  for (int mt = 0; mt < 4; ++mt)
#pragma unroll
    for (int nt = 0; nt < 4; ++nt) {
      int n = col0 + 64 * wn + 16 * nt + lm;
      float bv = bias[n];
#pragma unroll
      for (int r = 0; r < 4; ++r) {
        int m = row0 + 64 * wm + 16 * mt + 4 * lq + r;
        out[(size_t)m * 512 + n] = acc[mt][nt][r] + bv;
      }
    }
}

// ---------------------------------------------------------------------------
extern "C" void kernel_launch(void* const* d_in, const int* in_sizes, int n_in,
                              void* d_out, int out_size, void* d_ws, size_t ws_size,
                              hipStream_t stream) {
  const float* x    = (const float*)d_in[0];
  const float* Wqkv = (const float*)d_in[1];
  const float* Wout = (const float*)d_in[2];
  const float* bout = (const float*)d_in[3];
  const float* rker = (const float*)d_in[4];
  float* out = (float*)d_out;
  float* ws = (float*)d_ws;

  // workspace layout (float-element offsets), total ~186.6 MB
  ush*   vT     = (ush*)(ws);                          // 8388608 ush (v transposed)
  ush*   q_bf   = (ush*)(ws + 4194304);                // 8388608 ush
  float* regA   = ws + 8388608;                        // 8388608 f: k_bf -> outp
  float* regB   = ws + 16777216;                       // 8388608 f: xh+xl -> outph+outpl
  float* qlm    = ws + 25165824;                       // 524288
  float* klm    = ws + 25690112;                       // 524288
  float* regC   = ws + 26214400;                       // 2097152 f: t2(h,l) / ttT
  float* a2reg  = ws + 28311552;                       // 2097152 f: a2h+a2l
  float* zAreg  = ws + 30408704;                       // 4194304 f
  float* zBreg  = ws + 34603008;                       // 4194304 f
  float* xzreg  = ws + 38797312;                       // 4194304 f: Y + bar (later O_part/l_part)
  float* t3reg  = ws + 43515904;                       // 2097152 f: U (later svB)
  float* wqkvT  = ws + 45613056;                       // 786432 f
  float* woutT  = ws + 46399488;                       // 262144 f
  float* red    = ws + 46661632;                       // 128

  ush* k_bf  = (ush*)regA;
  float* outp = regA;
  ush* xh = (ush*)regB;                 // 8388608 ush
  ush* xl = (ush*)(regB + 4194304);     // 8388608 ush
  ush* outph = (ush*)regB;
  ush* outpl = (ush*)(regB + 4194304);
  ush* a2h = (ush*)a2reg;               // 2097152 ush each
  ush* a2l = (ush*)(a2reg + 1048576);
  ush* zA_[4] = {(ush*)zAreg, (ush*)(zAreg + 1048576), (ush*)(zAreg + 2097152), (ush*)(zAreg + 3145728)};
  ush* zB_[4] = {(ush*)zBreg, (ush*)(zBreg + 1048576), (ush*)(zBreg + 2097152), (ush*)(zBreg + 3145728)};
  ush* Y_h  = (ush*)xzreg;              // Y = a2@z, symmetric (row-major only)
  ush* Y_l  = (ush*)(xzreg + 1048576);
  unsigned* bar = (unsigned*)(xzreg + 2097152);  // 32 batches x 64 uints
  ush* t2_h = (ush*)regC;               // t2 = 7Y - Y^2, symmetric (row-major)
  ush* t2_l = (ush*)(regC + 1048576);
  ush* U_h  = (ush*)t3reg;              // U = z@Y (row-major)
  ush* U_l  = (ush*)(t3reg + 1048576);
  float* O_part = xzreg;                // after pinv
  float* l_part = xzreg + 2097152;
  ush* svB_h = (ush*)t3reg;             // after pinv
  ush* svB_l = (ush*)(t3reg + 262144);
  ush* ttT   = (ush*)regC;              // after pinv
  ush* wqkvT_h = (ush*)wqkvT;
  ush* wqkvT_l = (ush*)(wqkvT + 393216);
  ush* woutT_h = (ush*)woutT;
  ush* woutT_l = (ush*)(woutT + 131072);

  // --- pre-splits ---
  split_flat<<<2048, 256, 0, stream>>>(x, xh, xl, 2097152);
  transpose_split_w<<<dim3(48, 16), 256, 0, stream>>>(Wqkv, wqkvT_h, wqkvT_l, 512, 1536);
  transpose_split_w<<<dim3(16, 16), 256, 0, stream>>>(Wout, woutT_h, woutT_l, 512, 512);

  // --- qkv + landmarks (+ direct vT) ---
  qkv_mfma<<<dim3(128, 12), 256, 0, stream>>>(xh, xl, wqkvT_h,
                                              q_bf, k_bf, vT, qlm, klm);

  // --- attn2 + pinv init ---
  sim2_softmax<<<8192, 256, 0, stream>>>(qlm, klm, a2h, a2l);
  colmax<<<32, 256, 0, stream>>>(a2h, red);
  finalize_scale<<<1, 64, 0, stream>>>(red, bar);
  zinit_split<<<dim3(8, 8, 32), 256, 0, stream>>>(a2h, a2l, red,
                                                  zA_[0], zA_[1], zA_[2], zA_[3]);

  // --- pinv Newton-Schulz: entire 6-iter, 3-stage chain in ONE dispatch ---
  pinv_fused<<<512, 256, 0, stream>>>(
      a2h, a2l,
      zA_[0], zA_[1], zA_[2], zA_[3],
      zB_[0], zB_[1], zB_[2], zB_[3],
      Y_h, Y_l, t2_h, t2_l, U_h, U_l, bar);
  // final z (attn2_inv) lands in zA_ (full split)

  // --- sim3 (flash) ---
  sim3_mfma<<<dim3(4, NCH, 32), 256, 0, stream>>>(qlm, k_bf, vT, O_part, l_part);
  sim3_finalize<<<dim3(8, 32), 256, 0, stream>>>(O_part, l_part, svB_h, svB_l);

  // --- tt = attn2_inv @ sv (write ttT = tt^T plain bf16) ---
  bgemm_split<<<dim3(4, 1, 32), 256, 0, stream>>>(
      zA_[0], zA_[1], svB_h, svB_l,
      nullptr, nullptr, nullptr, nullptr,
      nullptr, nullptr, ttT, nullptr, 256, 64, 256, 0.f, 0.f, -1.f);

  // --- attn1 + conv + output projection ---
  attn1_mfma<<<dim3(64, 32), 256, 0, stream>>>(q_bf, klm, ttT, outp);
  conv_add_split<<<dim3(64, 32), 256, 0, stream>>>(outp, vT, rker, outph, outpl);
  out_gemm_split<<<dim3(128, 4), 256, 0, stream>>>(outph, outpl, woutT_h, woutT_l, bout, out);
}

// Round 6
// 714.225 us; speedup vs baseline: 2.6669x; 2.3239x over previous
//
#include <hip/hip_runtime.h>
#include <math.h>

// Problem constants
constexpr int BATCH = 4;
constexpr int SEQ   = 4096;
constexpr int DIMC  = 512;
constexpr int NH    = 8;
constexpr int HD    = 64;
constexpr int NLM   = 256;   // landmarks M
constexpr int LWIN  = 16;    // SEQ / NLM
constexpr int KWIN  = 33;
constexpr int BH    = BATCH * NH; // 32

typedef __attribute__((ext_vector_type(8))) short  bfrag;  // 8 bf16 for MFMA A/B
typedef __attribute__((ext_vector_type(4))) float  ffrag;  // MFMA C/D
typedef __attribute__((ext_vector_type(8))) unsigned short us8;
typedef __attribute__((ext_vector_type(4))) unsigned short us4;
typedef unsigned short ush;

__device__ __forceinline__ ush f2bf(float f) {
  unsigned u = __builtin_bit_cast(unsigned, f);
  return (ush)((u + 0x7FFFu + ((u >> 16) & 1u)) >> 16);
}
__device__ __forceinline__ float bf2f(ush h) {
  unsigned u = ((unsigned)h) << 16;
  return __builtin_bit_cast(float, u);
}
__device__ __forceinline__ void splitf(float f, ush& h, ush& l) {
  h = f2bf(f);
  l = f2bf(f - bf2f(h));
}
// async global->LDS, 16B per lane: LDS dest = base + lane*16 (wave-uniform base)
__device__ __forceinline__ void gl_lds16(const ush* g, ush* l) {
  __builtin_amdgcn_global_load_lds(
      (const __attribute__((address_space(1))) void*)g,
      (__attribute__((address_space(3))) void*)l, 16, 0, 0);
}

// ---------------------------------------------------------------------------
// split_flat: fp32 -> (hi, lo) bf16, elementwise (x pre-split). Grid-stride.
// ---------------------------------------------------------------------------
__global__ void split_flat(const float* __restrict__ src, ush* __restrict__ oh,
                           ush* __restrict__ ol, int n4) {
  for (int i = blockIdx.x * 256 + threadIdx.x; i < n4; i += gridDim.x * 256) {
    float4 f = ((const float4*)src)[i];
    us4 h, l;
    float fs[4] = {f.x, f.y, f.z, f.w};
#pragma unroll
    for (int j = 0; j < 4; ++j) {
      ush hh, ll;
      splitf(fs[j], hh, ll);
      h[j] = hh; l[j] = ll;
    }
    ((us4*)oh)[i] = h;
    ((us4*)ol)[i] = l;
  }
}

// ---------------------------------------------------------------------------
// transpose_split_w: in [R][C] fp32 -> out [C][R] hi/lo bf16 (weights)
// ---------------------------------------------------------------------------
__global__ __launch_bounds__(256) void transpose_split_w(const float* __restrict__ in,
                                                         ush* __restrict__ oh,
                                                         ush* __restrict__ ol,
                                                         int R, int C) {
  __shared__ float T[32][33];
  const int tid = threadIdx.x;
  const int c0 = blockIdx.x * 32, r0 = blockIdx.y * 32;
#pragma unroll
  for (int u = 0; u < 4; ++u) {
    int r = (tid >> 5) * 4 + u, cl = tid & 31;
    T[r][cl] = in[(size_t)(r0 + r) * C + c0 + cl];
  }
  __syncthreads();
#pragma unroll
  for (int u = 0; u < 4; ++u) {
    int cl = (tid >> 5) * 4 + u, rl = tid & 31;
    float f = T[rl][cl];
    ush h, l; splitf(f, h, l);
    size_t o = (size_t)(c0 + cl) * R + r0 + rl;
    oh[o] = h; ol[o] = l;
  }
}

// ---------------------------------------------------------------------------
// K1: qkv MFMA GEMM — 2-product split (x split, W hi-only; dropped x_hi@W_lo
// term ~1.8e-3/elem == same order as bf16 output rounding; r4/r5-verified,
// absmax unchanged 0.0039). BM=BN=128, BK=32, 256 thr, LDS 30KB.
// Epilogue: q/k bf16 + landmark pooling; v written DIRECTLY TRANSPOSED.
// ---------------------------------------------------------------------------
__global__ __launch_bounds__(256) void qkv_mfma(const ush* __restrict__ xh,
                                                const ush* __restrict__ xl,
                                                const ush* __restrict__ wTh,
                                                ush* __restrict__ q_bf,
                                                ush* __restrict__ k_bf,
                                                ush* __restrict__ vT,
                                                float* __restrict__ qlm,
                                                float* __restrict__ klm) {
  __shared__ ush Ash[128][40], Asl[128][40];
  __shared__ ush Bsh[128][40];
  const int tid = threadIdx.x;
  const int w = tid >> 6, lane = tid & 63;
  const int lm = lane & 15, lq = lane >> 4;
  const int wm = w >> 1, wn = w & 1;
  const int row0 = blockIdx.x * 128, col0 = blockIdx.y * 128;
  const ffrag fz = {0.f, 0.f, 0.f, 0.f};
  ffrag acc[4][4];
#pragma unroll
  for (int i = 0; i < 4; ++i)
#pragma unroll
    for (int j = 0; j < 4; ++j) acc[i][j] = fz;

  const int sm = tid >> 1, skoff = (tid & 1) * 16;
  for (int k0 = 0; k0 < 512; k0 += 32) {
    __syncthreads();
    {
      size_t ao = (size_t)(row0 + sm) * 512 + k0 + skoff;
      *(us8*)&Ash[sm][skoff]     = *(const us8*)&xh[ao];
      *(us8*)&Ash[sm][skoff + 8] = *(const us8*)&xh[ao + 8];
      *(us8*)&Asl[sm][skoff]     = *(const us8*)&xl[ao];
      *(us8*)&Asl[sm][skoff + 8] = *(const us8*)&xl[ao + 8];
      size_t bo = (size_t)(col0 + sm) * 512 + k0 + skoff;
      *(us8*)&Bsh[sm][skoff]     = *(const us8*)&wTh[bo];
      *(us8*)&Bsh[sm][skoff + 8] = *(const us8*)&wTh[bo + 8];
    }
    __syncthreads();
    bfrag ah[4], al[4], bh[4];
#pragma unroll
    for (int mt = 0; mt < 4; ++mt) {
      ah[mt] = *(const bfrag*)&Ash[64 * wm + 16 * mt + lm][8 * lq];
      al[mt] = *(const bfrag*)&Asl[64 * wm + 16 * mt + lm][8 * lq];
    }
#pragma unroll
    for (int nt = 0; nt < 4; ++nt)
      bh[nt] = *(const bfrag*)&Bsh[64 * wn + 16 * nt + lm][8 * lq];
#pragma unroll
    for (int mt = 0; mt < 4; ++mt)
#pragma unroll
      for (int nt = 0; nt < 4; ++nt) {
        acc[mt][nt] = __builtin_amdgcn_mfma_f32_16x16x32_bf16(ah[mt], bh[nt], acc[mt][nt], 0, 0, 0);
        acc[mt][nt] = __builtin_amdgcn_mfma_f32_16x16x32_bf16(al[mt], bh[nt], acc[mt][nt], 0, 0, 0);
      }
  }
  // epilogue
#pragma unroll
  for (int mt = 0; mt < 4; ++mt) {
    int rbase = row0 + 64 * wm + 16 * mt;      // 16-aligned -> single window
    int b = rbase >> 12;
    int ntok_base = rbase & 4095;
    int win = ntok_base >> 4;
#pragma unroll
    for (int nt = 0; nt < 4; ++nt) {
      int n_local = 64 * wn + 16 * nt;          // frag col base (h uniform)
      int col = col0 + n_local + lm;
      int which = col >> 9;                     // 0=q 1=k 2=v
      int h = (col >> 6) & 7;
      int d = col & 63;
      int bh_i = b * NH + h;
      float scale = (which == 0) ? 0.125f : 1.0f;
      float vals[4];
      float s = 0.f;
#pragma unroll
      for (int r = 0; r < 4; ++r) {
        vals[r] = acc[mt][nt][r] * scale;
        s += vals[r];
      }
      if (which == 2) {
        // direct transposed store: vT[bh][d][ntok] (4 contiguous ntok/lane)
        ush* dst = &vT[((size_t)bh_i * HD + d) * SEQ + ntok_base + 4 * lq];
#pragma unroll
        for (int r = 0; r < 4; ++r) dst[r] = f2bf(vals[r]);
      } else {
        ush* dst = which == 0 ? q_bf : k_bf;
#pragma unroll
        for (int r = 0; r < 4; ++r) {
          int ntok = ntok_base + 4 * lq + r;
          dst[((size_t)bh_i * SEQ + ntok) * HD + d] = f2bf(vals[r]);
        }
        s += __shfl_xor(s, 16);
        s += __shfl_xor(s, 32);
        if (lq == 0) {
          float* lmdst = which == 0 ? qlm : klm;
          lmdst[((size_t)bh_i * NLM + win) * HD + d] = s * (1.0f / LWIN);
        }
      }
    }
  }
}

// ---------------------------------------------------------------------------
// K3: attn2 = softmax(qlm @ klm^T) rows -> split bf16 (a2h/a2l)
// ---------------------------------------------------------------------------
__global__ __launch_bounds__(256) void sim2_softmax(const float* __restrict__ qlm,
                                                    const float* __restrict__ klm,
                                                    ush* __restrict__ a2h,
                                                    ush* __restrict__ a2l) {
  int i = blockIdx.x & 255;
  int bh = blockIdx.x >> 8;
  int j = threadIdx.x;
  __shared__ float qrow[64];
  __shared__ float red[256];
  if (j < 64) qrow[j] = qlm[((size_t)bh * NLM + i) * HD + j];
  __syncthreads();
  const float* kr = klm + ((size_t)bh * NLM + j) * HD;
  float s = 0.f;
#pragma unroll
  for (int d = 0; d < 64; d += 4) {
    float4 kv = *(const float4*)&kr[d];
    s += qrow[d] * kv.x + qrow[d + 1] * kv.y + qrow[d + 2] * kv.z + qrow[d + 3] * kv.w;
  }
  red[j] = s; __syncthreads();
  for (int off = 128; off > 0; off >>= 1) {
    if (j < off) red[j] = fmaxf(red[j], red[j + off]);
    __syncthreads();
  }
  float mx = red[0]; __syncthreads();
  float e = expf(s - mx);
  red[j] = e; __syncthreads();
  for (int off = 128; off > 0; off >>= 1) {
    if (j < off) red[j] += red[j + off];
    __syncthreads();
  }
  float val = e / red[0];
  size_t o = ((size_t)bh * NLM + i) * NLM + j;
  ush h, l; splitf(val, h, l);
  a2h[o] = h; a2l[o] = l;
}

// ---------------------------------------------------------------------------
// K4a: per-bh column sums of attn2 (hi plane only), block max.
// attn2 rows are softmax rows -> row sums are exactly 1.
// ---------------------------------------------------------------------------
__global__ __launch_bounds__(256) void colmax(const ush* __restrict__ a2h,
                                              float* __restrict__ red) {
  int bh = blockIdx.x;
  int t = threadIdx.x;
  const size_t base = (size_t)bh * NLM * NLM;
  float cs = 0.f;
  for (int i = 0; i < NLM; ++i) cs += bf2f(a2h[base + (size_t)i * NLM + t]);
  __shared__ float r1[256];
  r1[t] = cs; __syncthreads();
  for (int off = 128; off > 0; off >>= 1) {
    if (t < off) r1[t] = fmaxf(r1[t], r1[t + off]);
    __syncthreads();
  }
  if (t == 0) red[bh] = r1[0];
}

__global__ void finalize_scale(float* __restrict__ red) {
  if (threadIdx.x == 0) {
    float m1 = -1e30f;
    for (int i = 0; i < BH; ++i) m1 = fmaxf(m1, red[i]);
    red[64] = 1.0f / m1;   // row-sum max == 1 exactly (softmax rows)
  }
}

// ---------------------------------------------------------------------------
// K4c: z0 = attn2^T * invscale, A-form + B-form splits
// ---------------------------------------------------------------------------
__global__ __launch_bounds__(256) void zinit_split(const ush* __restrict__ a2h,
                                                   const ush* __restrict__ a2l,
                                                   const float* __restrict__ red,
                                                   ush* __restrict__ zAh, ush* __restrict__ zAl,
                                                   ush* __restrict__ zBh, ush* __restrict__ zBl) {
  __shared__ float T[32][33];
  const int tid = threadIdx.x;
  const int bh = blockIdx.z;
  const int j0 = blockIdx.x * 32, i0 = blockIdx.y * 32;
  const float s = red[64];
  const size_t base = (size_t)bh * NLM * NLM;
#pragma unroll
  for (int u = 0; u < 4; ++u) {
    int jl = (tid >> 5) * 4 + u, il = tid & 31;
    size_t o = base + (size_t)(j0 + jl) * NLM + i0 + il;
    float a = (bf2f(a2h[o]) + bf2f(a2l[o])) * s;
    T[jl][il] = a;
    ush h, l; splitf(a, h, l);
    zBh[o] = h; zBl[o] = l;   // zB[j][i] = a2[j][i]*s
  }
  __syncthreads();
#pragma unroll
  for (int u = 0; u < 4; ++u) {
    int il = (tid >> 5) * 4 + u, jl = tid & 31;
    float a = T[jl][il];
    ush h, l; splitf(a, h, l);
    size_t o = base + (size_t)(i0 + il) * NLM + j0 + jl;  // zA[i][j] = a2[j][i]*s
    zAh[o] = h; zAl[o] = l;
  }
}

// ---------------------------------------------------------------------------
// K5 core: one 64x64 tile of C = A@B^T(stored) with split-bf16 planes.
// m97 structure: global_load_lds staging, BK=64. Null lo-pointers skip planes.
// Epilogue: y = coef * (alpha*E1 + beta*E2 - C); outputs row-major (oA) and/or
// transposed B-form (oB). FORCEINLINE ONLY (noinline corrupted the
// global_load_lds path -> r2 NaN).
// NOTE (r4/r5 post-mortem): fused-chain variants with in-kernel barriers are
// structurally HBM-bound (~550 MB traffic/dispatch: per-XCD L2 invalidated
// at every inter-block barrier while a batch's blocks span all 8 XCDs).
// Launch-boundary sync keeps L2/LLC reuse intact — 4x faster. Do not re-fuse.
// ---------------------------------------------------------------------------
__device__ __forceinline__ void stage_gemm(
    ush (*S)[2][8][64][8],   // LDS [2][2][8][64][8] = 32 KB
    const ush* Ah, const ush* Al, const ush* Bh, const ush* Bl,
    const ush* E1h, const ush* E1l, const ush* E2h, const ush* E2l,
    ush* oAh, ush* oAl, ush* oBh, ush* oBl,
    int M, int N, int K, float alpha, float beta, float coef,
    int bx, int by, int batch, int tid) {
  const size_t abase = (size_t)batch * M * K;
  const size_t bbase = (size_t)batch * N * K;
  const size_t ebase = (size_t)batch * M * N;
  const int w = tid >> 6, lane = tid & 63;
  const int lm = lane & 15, lq = lane >> 4;
  const int wm = w >> 1, wn = w & 1;
  const int row0 = bx * 64, col0 = by * 64;
  const bool uAl = (Al != nullptr);
  const bool uBl = (Bl != nullptr);
  const ffrag fz = {0.f, 0.f, 0.f, 0.f};
  ffrag acc[2][2] = {{fz, fz}, {fz, fz}};

  const size_t arow = abase + (size_t)(row0 + lane) * K;   // per-lane
  const size_t brow = bbase + (size_t)(col0 + lane) * K;

  for (int k0 = 0; k0 < K; k0 += 64) {
    __syncthreads();
    // wave w stages k-chunks {2w, 2w+1} for A and B (lo planes only if used)
#pragma unroll
    for (int ci = 0; ci < 2; ++ci) {
      int c = 2 * w + ci;
      gl_lds16(&Ah[arow + k0 + 8 * c], &S[0][0][c][0][0]);
      gl_lds16(&Bh[brow + k0 + 8 * c], &S[1][0][c][0][0]);
      if (uAl) gl_lds16(&Al[arow + k0 + 8 * c], &S[0][1][c][0][0]);
      if (uBl) gl_lds16(&Bl[brow + k0 + 8 * c], &S[1][1][c][0][0]);
    }
    __syncthreads();   // compiler emits vmcnt(0) drain here (m97 structure)
#pragma unroll
    for (int ks = 0; ks < 2; ++ks) {
      bfrag ah[2], al[2], bhf[2], blf[2];
#pragma unroll
      for (int mt = 0; mt < 2; ++mt) {
        ah[mt] = *(const bfrag*)&S[0][0][4 * ks + lq][32 * wm + 16 * mt + lm][0];
        if (uAl) al[mt] = *(const bfrag*)&S[0][1][4 * ks + lq][32 * wm + 16 * mt + lm][0];
      }
#pragma unroll
      for (int nt = 0; nt < 2; ++nt) {
        bhf[nt] = *(const bfrag*)&S[1][0][4 * ks + lq][32 * wn + 16 * nt + lm][0];
        if (uBl) blf[nt] = *(const bfrag*)&S[1][1][4 * ks + lq][32 * wn + 16 * nt + lm][0];
      }
#pragma unroll
      for (int mt = 0; mt < 2; ++mt)
#pragma unroll
        for (int nt = 0; nt < 2; ++nt) {
          acc[mt][nt] = __builtin_amdgcn_mfma_f32_16x16x32_bf16(ah[mt], bhf[nt], acc[mt][nt], 0, 0, 0);
          if (uAl) acc[mt][nt] = __builtin_amdgcn_mfma_f32_16x16x32_bf16(al[mt], bhf[nt], acc[mt][nt], 0, 0, 0);
          if (uBl) acc[mt][nt] = __builtin_amdgcn_mfma_f32_16x16x32_bf16(ah[mt], blf[nt], acc[mt][nt], 0, 0, 0);
        }
    }
  }
#pragma unroll
  for (int mt = 0; mt < 2; ++mt)
#pragma unroll
    for (int nt = 0; nt < 2; ++nt) {
      int n = col0 + 32 * wn + 16 * nt + lm;
#pragma unroll
      for (int r = 0; r < 4; ++r) {
        int m = row0 + 32 * wm + 16 * mt + 4 * lq + r;
        float c = acc[mt][nt][r];
        float e = 0.f;
        size_t eo = ebase + (size_t)m * N + n;
        if (E1h) {
          float t = bf2f(E1h[eo]);
          if (E1l) t += bf2f(E1l[eo]);
          e += alpha * t;
        }
        if (E2h) {
          float t = bf2f(E2h[eo]);
          if (E2l) t += bf2f(E2l[eo]);
          e += beta * t;
        }
        float y = coef * (e - c);
        ush h, l; splitf(y, h, l);
        if (oAh) {
          size_t o = ebase + (size_t)m * N + n;
          oAh[o] = h;
          if (oAl) oAl[o] = l;
        }
        if (oBh) {
          size_t o = (size_t)batch * N * M + (size_t)n * M + m;
          oBh[o] = h;
          if (oBl) oBl[o] = l;
        }
      }
    }
}

__global__ __launch_bounds__(256) void bgemm_split(
    const ush* Ah, const ush* Al, const ush* Bh, const ush* Bl,
    const ush* E1h, const ush* E1l, const ush* E2h, const ush* E2l,
    ush* oAh, ush* oAl, ush* oBh, ush* oBl,
    int M, int N, int K, float alpha, float beta, float coef) {
  __shared__ ush S[2][2][8][64][8];
  stage_gemm(S, Ah, Al, Bh, Bl, E1h, E1l, E2h, E2l, oAh, oAl, oBh, oBl,
             M, N, K, alpha, beta, coef, blockIdx.x, blockIdx.y, blockIdx.z,
             threadIdx.x);
}

// ---------------------------------------------------------------------------
// ns_s2: batched stage-2 of the 3-stage NS iteration. blockIdx.z = batch*2 +
// which. which=0: t2 = 7Y - Y@Y (Y symmetric -> Y row-major serves as B).
// which=1: U = z@Y. Both outputs row-major only (t2 symmetric; U used as
// A-operand/E-term downstream). r3-verified.
// ---------------------------------------------------------------------------
__global__ __launch_bounds__(256) void ns_s2(
    const ush* Yh, const ush* Yl, const ush* zh, const ush* zl,
    ush* t2h, ush* t2l, ush* Uh, ush* Ul) {
  __shared__ ush S[2][2][8][64][8];
  const int bz = blockIdx.z, batch = bz >> 1;
  if ((bz & 1) == 0) {
    stage_gemm(S, Yh, Yl, Yh, Yl, Yh, Yl, nullptr, nullptr,
               t2h, t2l, nullptr, nullptr,
               256, 256, 256, 7.f, 0.f, 1.f,
               blockIdx.x, blockIdx.y, batch, threadIdx.x);
  } else {
    stage_gemm(S, zh, zl, Yh, Yl, nullptr, nullptr, nullptr, nullptr,
               Uh, Ul, nullptr, nullptr,
               256, 256, 256, 0.f, 0.f, -1.f,
               blockIdx.x, blockIdx.y, batch, threadIdx.x);
  }
}

// ---------------------------------------------------------------------------
// K6: sim3 flash via MFMA, no max-subtraction (scores tiny). n-split NCH ways.
// ---------------------------------------------------------------------------
constexpr int NCH = 4;
__global__ __launch_bounds__(256) void sim3_mfma(const float* __restrict__ qlm,
                                                 const ush* __restrict__ k_bf,
                                                 const ush* __restrict__ vT_bf,
                                                 float* __restrict__ O_part,
                                                 float* __restrict__ l_part) {
  constexpr int CHUNK = SEQ / NCH;  // 1024
  __shared__ ush Qs[64][72];
  __shared__ ush Ks[128][72];
  __shared__ ush Vs[64][136];
  __shared__ ush Ps[64][136];
  const int bh = blockIdx.z;
  const int m0 = blockIdx.x * 64;
  const int n_base = blockIdx.y * CHUNK;
  const int tid = threadIdx.x;
  const int w = tid >> 6, lane = tid & 63;
  const int lm = lane & 15, lq = lane >> 4;
  {
    int m = tid >> 2, off = (tid & 3) * 16;
    const float* src = &qlm[((size_t)bh * NLM + m0 + m) * HD + off];
    us8 o0, o1;
#pragma unroll
    for (int j = 0; j < 8; ++j) o0[j] = f2bf(src[j]);
#pragma unroll
    for (int j = 0; j < 8; ++j) o1[j] = f2bf(src[8 + j]);
    *(us8*)&Qs[m][off] = o0;
    *(us8*)&Qs[m][off + 8] = o1;
  }
  const ffrag fz = {0.f, 0.f, 0.f, 0.f};
  ffrag O[4] = {fz, fz, fz, fz};
  float lsum[4] = {0.f, 0.f, 0.f, 0.f};

  for (int n0 = 0; n0 < CHUNK; n0 += 128) {
    __syncthreads();
    {
      int n = tid >> 1, off = (tid & 1) * 32;
      const ush* src = &k_bf[((size_t)bh * SEQ + n_base + n0 + n) * HD + off];
#pragma unroll
      for (int u = 0; u < 4; ++u) *(us8*)&Ks[n][off + 8 * u] = *(const us8*)&src[8 * u];
    }
    {
      int d = tid >> 2, off = (tid & 3) * 32;
      const ush* src = &vT_bf[((size_t)bh * HD + d) * SEQ + n_base + n0 + off];
#pragma unroll
      for (int u = 0; u < 4; ++u) *(us8*)&Vs[d][off + 8 * u] = *(const us8*)&src[8 * u];
    }
    __syncthreads();
    ffrag S[8] = {fz, fz, fz, fz, fz, fz, fz, fz};
#pragma unroll
    for (int ks = 0; ks < 2; ++ks) {
      bfrag a = *(const bfrag*)&Qs[16 * w + lm][32 * ks + 8 * lq];
#pragma unroll
      for (int t = 0; t < 8; ++t) {
        bfrag b = *(const bfrag*)&Ks[16 * t + lm][32 * ks + 8 * lq];
        S[t] = __builtin_amdgcn_mfma_f32_16x16x32_bf16(a, b, S[t], 0, 0, 0);
      }
    }
#pragma unroll
    for (int t = 0; t < 8; ++t)
#pragma unroll
      for (int r = 0; r < 4; ++r) {
        float p = __expf(S[t][r]);
        lsum[r] += p;
        Ps[16 * w + 4 * lq + r][16 * t + lm] = f2bf(p);
      }
    __syncthreads();
#pragma unroll
    for (int kk = 0; kk < 4; ++kk) {
      bfrag a = *(const bfrag*)&Ps[16 * w + lm][32 * kk + 8 * lq];
#pragma unroll
      for (int t2 = 0; t2 < 4; ++t2) {
        bfrag b = *(const bfrag*)&Vs[16 * t2 + lm][32 * kk + 8 * lq];
        O[t2] = __builtin_amdgcn_mfma_f32_16x16x32_bf16(a, b, O[t2], 0, 0, 0);
      }
    }
  }
#pragma unroll
  for (int r = 0; r < 4; ++r) {
#pragma unroll
    for (int off = 1; off < 16; off <<= 1) lsum[r] += __shfl_xor(lsum[r], off);
  }
  const size_t pbase = (size_t)blockIdx.y * 32 + bh;
  if (lm == 0) {
#pragma unroll
    for (int r = 0; r < 4; ++r)
      l_part[pbase * NLM + m0 + 16 * w + 4 * lq + r] = lsum[r];
  }
#pragma unroll
  for (int t2 = 0; t2 < 4; ++t2)
#pragma unroll
    for (int r = 0; r < 4; ++r) {
      int m = m0 + 16 * w + 4 * lq + r;
      int d = 16 * t2 + lm;
      O_part[(pbase * NLM + m) * HD + d] = O[t2][r];
    }
}

// sim3_finalize: combine partials, write sv in B-form split ([d][m]).
// grid (8,32): blockIdx.x = {d-quarter (low 2 bits), m-half (bit 2)}.
__global__ __launch_bounds__(256) void sim3_finalize(const float* __restrict__ O_part,
                                                     const float* __restrict__ l_part,
                                                     ush* __restrict__ svBh,
                                                     ush* __restrict__ svBl) {
  __shared__ float T[128][17];
  __shared__ float ls[128];
  const int bh = blockIdx.y;
  const int d0 = (blockIdx.x & 3) * 16;
  const int m0 = (blockIdx.x >> 2) * 128;
  const int tid = threadIdx.x;
  if (tid < 128) {
    float s = 0.f;
#pragma unroll
    for (int c = 0; c < NCH; ++c) s += l_part[(size_t)(c * 32 + bh) * NLM + m0 + tid];
    ls[tid] = s;
  }
#pragma unroll
  for (int i = 0; i < 8; ++i) {
    int e = i * 256 + tid;          // [0, 2048)
    int m = e >> 4, dd = e & 15;
    float s = 0.f;
#pragma unroll
    for (int c = 0; c < NCH; ++c)
      s += O_part[(((size_t)(c * 32 + bh)) << 14) + (size_t)(m0 + m) * HD + d0 + dd];
    T[m][dd] = s;
  }
  __syncthreads();
#pragma unroll
  for (int i = 0; i < 8; ++i) {
    int e = i * 256 + tid;
    int dd = e >> 7, m = e & 127;
    float val = T[m][dd] / ls[m];
    ush h, l; splitf(val, h, l);
    size_t o = ((size_t)bh * HD + d0 + dd) * NLM + m0 + m;
    svBh[o] = h; svBl[o] = l;
  }
}

// ---------------------------------------------------------------------------
// K8: attn1 via MFMA: outp = softmax(q_bf @ klm^T) @ tt  (fp32 softmax)
// ---------------------------------------------------------------------------
__global__ __launch_bounds__(256) void attn1_mfma(const ush* __restrict__ q_bf,
                                                  const float* __restrict__ klm,
                                                  const ush* __restrict__ ttT,
                                                  float* __restrict__ outp) {
  __shared__ ush bufA[256 * 72];   // klm bf16 [256][72] then ttT [64][264]
  __shared__ ush bufB[64 * 264];   // qs [64][72] then Ps [64][264]
  const int bh = blockIdx.y;
  const int b = bh >> 3, h = bh & 7;
  const int i0 = blockIdx.x * 64;
  const int tid = threadIdx.x;
  const int w = tid >> 6, lane = tid & 63;
  const int lm = lane & 15, lq = lane >> 4;
  {
    int m = tid >> 2, off = (tid & 3) * 16;
    const ush* src = &q_bf[((size_t)bh * SEQ + i0 + m) * HD + off];
    *(us8*)&bufB[m * 72 + off] = *(const us8*)src;
    *(us8*)&bufB[m * 72 + off + 8] = *(const us8*)&src[8];
  }
  {
    const float* kb = klm + (size_t)bh * NLM * HD;
#pragma unroll
    for (int u = 0; u < 16; ++u) {
      int e4 = u * 256 + tid;
      float4 f = ((const float4*)kb)[e4];
      int row = e4 >> 4, col = (e4 & 15) * 4;
      ush* p = &bufA[row * 72 + col];
      p[0] = f2bf(f.x); p[1] = f2bf(f.y); p[2] = f2bf(f.z); p[3] = f2bf(f.w);
    }
  }
  __syncthreads();
  const ffrag fz = {0.f, 0.f, 0.f, 0.f};
  ffrag S[16];
#pragma unroll
  for (int t = 0; t < 16; ++t) S[t] = fz;
#pragma unroll
  for (int ks = 0; ks < 2; ++ks) {
    bfrag a = *(const bfrag*)&bufB[(16 * w + lm) * 72 + 32 * ks + 8 * lq];
#pragma unroll
    for (int t = 0; t < 16; ++t) {
      bfrag bb = *(const bfrag*)&bufA[(16 * t + lm) * 72 + 32 * ks + 8 * lq];
      S[t] = __builtin_amdgcn_mfma_f32_16x16x32_bf16(a, bb, S[t], 0, 0, 0);
    }
  }
  float rinv[4];
  float ev[16][4];
#pragma unroll
  for (int r = 0; r < 4; ++r) {
    float mx = -INFINITY;
#pragma unroll
    for (int t = 0; t < 16; ++t) mx = fmaxf(mx, S[t][r]);
#pragma unroll
    for (int off = 1; off < 16; off <<= 1) mx = fmaxf(mx, __shfl_xor(mx, off));
    float sm = 0.f;
#pragma unroll
    for (int t = 0; t < 16; ++t) { ev[t][r] = __expf(S[t][r] - mx); sm += ev[t][r]; }
#pragma unroll
    for (int off = 1; off < 16; off <<= 1) sm += __shfl_xor(sm, off);
    rinv[r] = 1.0f / sm;
  }
  __syncthreads();
#pragma unroll
  for (int t = 0; t < 16; ++t)
#pragma unroll
    for (int r = 0; r < 4; ++r)
      bufB[(16 * w + 4 * lq + r) * 264 + 16 * t + lm] = f2bf(ev[t][r]);
  {
    const ush* tb = ttT + (size_t)bh * HD * NLM;
#pragma unroll
    for (int u = 0; u < 8; ++u) {
      int e8 = u * 256 + tid;
      int row = e8 >> 5, col = (e8 & 31) * 8;
      *(us8*)&bufA[row * 264 + col] = *(const us8*)&tb[row * NLM + col];
    }
  }
  __syncthreads();
  ffrag O[4] = {fz, fz, fz, fz};
#pragma unroll
  for (int kk = 0; kk < 8; ++kk) {
    bfrag a = *(const bfrag*)&bufB[(16 * w + lm) * 264 + 32 * kk + 8 * lq];
#pragma unroll
    for (int t2 = 0; t2 < 4; ++t2) {
      bfrag bb = *(const bfrag*)&bufA[(16 * t2 + lm) * 264 + 32 * kk + 8 * lq];
      O[t2] = __builtin_amdgcn_mfma_f32_16x16x32_bf16(a, bb, O[t2], 0, 0, 0);
    }
  }
#pragma unroll
  for (int t2 = 0; t2 < 4; ++t2)
#pragma unroll
    for (int r = 0; r < 4; ++r) {
      int i = i0 + 16 * w + 4 * lq + r;
      int d = 16 * t2 + lm;
      outp[((size_t)b * SEQ + i) * DIMC + h * HD + d] = O[t2][r] * rinv[r];
    }
}

// ---------------------------------------------------------------------------
// K9: conv add + split: outp(fp32) + depthwise conv(vT) -> outph/outpl
// ---------------------------------------------------------------------------
__global__ __launch_bounds__(256) void conv_add_split(const float* __restrict__ outp,
                                                      const ush* __restrict__ vT,
                                                      const float* __restrict__ kern,
                                                      ush* __restrict__ oh,
                                                      ush* __restrict__ ol) {
  __shared__ float vt[64 * 97];   // [d][96+1], cols n0-16 .. n0+79
  __shared__ float ks[KWIN];
  const int bh = blockIdx.y;
  const int b = bh >> 3, hh = bh & 7;
  const int n0 = blockIdx.x * 64;
  const int tid = threadIdx.x;
  if (tid < KWIN) ks[tid] = kern[hh * KWIN + tid];
  for (int e = tid; e < 64 * 96; e += 256) {
    int d = e / 96, c = e % 96;
    int n = n0 - 16 + c;
    vt[d * 97 + c] = (n >= 0 && n < SEQ) ? bf2f(vT[((size_t)bh * HD + d) * SEQ + n]) : 0.f;
  }
  __syncthreads();
  const int d = tid & 63, g = tid >> 6;
  float wreg[48];
#pragma unroll
  for (int j = 0; j < 48; ++j) wreg[j] = vt[d * 97 + g * 16 + j];
#pragma unroll
  for (int nn = 0; nn < 16; ++nn) {
    float s = 0.f;
#pragma unroll
    for (int t = 0; t < KWIN; ++t) s = fmaf(ks[t], wreg[nn + t], s);
    int n = n0 + g * 16 + nn;
    size_t o = ((size_t)b * SEQ + n) * DIMC + hh * HD + d;
    float val = outp[o] + s;
    ush h, l; splitf(val, h, l);
    oh[o] = h; ol[o] = l;
  }
}

// ---------------------------------------------------------------------------
// K10: out = outp_split @ WoutT_split + bias (3-product: final projection is
// precision-critical, keep full split). BM=BN=128, grid (128, 4)
// ---------------------------------------------------------------------------
__global__ __launch_bounds__(256) void out_gemm_split(const ush* __restrict__ ah_g,
                                                      const ush* __restrict__ al_g,
                                                      const ush* __restrict__ bh_g,
                                                      const ush* __restrict__ bl_g,
                                                      const float* __restrict__ bias,
                                                      float* __restrict__ out) {
  __shared__ ush Ash[128][40], Asl[128][40];
  __shared__ ush Bsh[128][40], Bsl[128][40];
  const int tid = threadIdx.x;
  const int w = tid >> 6, lane = tid & 63;
  const int lm = lane & 15, lq = lane >> 4;
  const int wm = w >> 1, wn = w & 1;
  const int row0 = blockIdx.x * 128, col0 = blockIdx.y * 128;
  const ffrag fz = {0.f, 0.f, 0.f, 0.f};
  ffrag acc[4][4];
#pragma unroll
  for (int i = 0; i < 4; ++i)
#pragma unroll
    for (int j = 0; j < 4; ++j) acc[i][j] = fz;

  const int sm = tid >> 1, skoff = (tid & 1) * 16;
  for (int k0 = 0; k0 < 512; k0 += 32) {
    __syncthreads();
    {
      size_t ao = (size_t)(row0 + sm) * 512 + k0 + skoff;
      *(us8*)&Ash[sm][skoff]     = *(const us8*)&ah_g[ao];
      *(us8*)&Ash[sm][skoff + 8] = *(const us8*)&ah_g[ao + 8];
      *(us8*)&Asl[sm][skoff]     = *(const us8*)&al_g[ao];
      *(us8*)&Asl[sm][skoff + 8] = *(const us8*)&al_g[ao + 8];
      size_t bo = (size_t)(col0 + sm) * 512 + k0 + skoff;
      *(us8*)&Bsh[sm][skoff]     = *(const us8*)&bh_g[bo];
      *(us8*)&Bsh[sm][skoff + 8] = *(const us8*)&bh_g[bo + 8];
      *(us8*)&Bsl[sm][skoff]     = *(const us8*)&bl_g[bo];
      *(us8*)&Bsl[sm][skoff + 8] = *(const us8*)&bl_g[bo + 8];
    }
    __syncthreads();
    bfrag ah[4], al[4], bh[4], bl[4];
#pragma unroll
    for (int mt = 0; mt < 4; ++mt) {
      ah[mt] = *(const bfrag*)&Ash[64 * wm + 16 * mt + lm][8 * lq];
      al[mt] = *(const bfrag*)&Asl[64 * wm + 16 * mt + lm][8 * lq];
    }
#pragma unroll
    for (int nt = 0; nt < 4; ++nt) {
      bh[nt] = *(const bfrag*)&Bsh[64 * wn + 16 * nt + lm][8 * lq];
      bl[nt] = *(const bfrag*)&Bsl[64 * wn + 16 * nt + lm][8 * lq];
    }
#pragma unroll
    for (int mt = 0; mt < 4; ++mt)
#pragma unroll
      for (int nt = 0; nt < 4; ++nt) {
        acc[mt][nt] = __builtin_amdgcn_mfma_f32_16x16x32_bf16(ah[mt], bh[nt], acc[mt][nt], 0, 0, 0);
        acc[mt][nt] = __builtin_amdgcn_mfma_f32_16x16x32_bf16(al[mt], bh[nt], acc[mt][nt], 0, 0, 0);
        acc[mt][nt] = __builtin_amdgcn_mfma_f32_16x16x32_bf16(ah[mt], bl[nt], acc[mt][nt], 0, 0, 0);
      }
  }
#pragma unroll
  for (int mt = 0; mt < 4; ++mt)
#pragma unroll
    for (int nt = 0; nt < 4; ++nt) {
      int n = col0 + 64 * wn + 16 * nt + lm;
      float bv = bias[n];
#pragma unroll
      for (int r = 0; r < 4; ++r) {
        int m = row0 + 64 * wm + 16 * mt + 4 * lq + r;
        out[(size_t)m * 512 + n] = acc[mt][nt][r] + bv;
      }
    }
}

// ---------------------------------------------------------------------------
extern "C" void kernel_launch(void* const* d_in, const int* in_sizes, int n_in,
                              void* d_out, int out_size, void* d_ws, size_t ws_size,
                              hipStream_t stream) {
  const float* x    = (const float*)d_in[0];
  const float* Wqkv = (const float*)d_in[1];
  const float* Wout = (const float*)d_in[2];
  const float* bout = (const float*)d_in[3];
  const float* rker = (const float*)d_in[4];
  float* out = (float*)d_out;
  float* ws = (float*)d_ws;

  // workspace layout (float-element offsets), total ~186.6 MB
  ush*   vT     = (ush*)(ws);                          // 8388608 ush (v transposed)
  ush*   q_bf   = (ush*)(ws + 4194304);                // 8388608 ush
  float* regA   = ws + 8388608;                        // 8388608 f: k_bf -> outp
  float* regB   = ws + 16777216;                       // 8388608 f: xh+xl -> outph+outpl
  float* qlm    = ws + 25165824;                       // 524288
  float* klm    = ws + 25690112;                       // 524288
  float* regC   = ws + 26214400;                       // 2097152 f: t2(h,l) / ttT
  float* a2reg  = ws + 28311552;                       // 2097152 f: a2h+a2l
  float* zAreg  = ws + 30408704;                       // 4194304 f
  float* zBreg  = ws + 34603008;                       // 4194304 f
  float* xzreg  = ws + 38797312;                       // 4194304 f: Y (later O_part/l_part)
  float* t3reg  = ws + 43515904;                       // 2097152 f: U (later svB)
  float* wqkvT  = ws + 45613056;                       // 786432 f
  float* woutT  = ws + 46399488;                       // 262144 f
  float* red    = ws + 46661632;                       // 128

  ush* k_bf  = (ush*)regA;
  float* outp = regA;
  ush* xh = (ush*)regB;                 // 8388608 ush
  ush* xl = (ush*)(regB + 4194304);     // 8388608 ush
  ush* outph = (ush*)regB;
  ush* outpl = (ush*)(regB + 4194304);
  ush* a2h = (ush*)a2reg;               // 2097152 ush each
  ush* a2l = (ush*)(a2reg + 1048576);
  ush* zA_[4] = {(ush*)zAreg, (ush*)(zAreg + 1048576), (ush*)(zAreg + 2097152), (ush*)(zAreg + 3145728)};
  ush* zB_[4] = {(ush*)zBreg, (ush*)(zBreg + 1048576), (ush*)(zBreg + 2097152), (ush*)(zBreg + 3145728)};
  ush* Y_h  = (ush*)xzreg;              // Y = a2@z, symmetric (row-major only)
  ush* Y_l  = (ush*)(xzreg + 1048576);
  ush* t2_h = (ush*)regC;               // t2 = 7Y - Y^2, symmetric (row-major)
  ush* t2_l = (ush*)(regC + 1048576);
  ush* U_h  = (ush*)t3reg;              // U = z@Y (row-major)
  ush* U_l  = (ush*)(t3reg + 1048576);
  float* O_part = xzreg;                // after pinv
  float* l_part = xzreg + 2097152;
  ush* svB_h = (ush*)t3reg;             // after pinv
  ush* svB_l = (ush*)(t3reg + 262144);
  ush* ttT   = (ush*)regC;              // after pinv
  ush* wqkvT_h = (ush*)wqkvT;
  ush* wqkvT_l = (ush*)(wqkvT + 393216);
  ush* woutT_h = (ush*)woutT;
  ush* woutT_l = (ush*)(woutT + 131072);

  // --- pre-splits ---
  split_flat<<<2048, 256, 0, stream>>>(x, xh, xl, 2097152);
  transpose_split_w<<<dim3(48, 16), 256, 0, stream>>>(Wqkv, wqkvT_h, wqkvT_l, 512, 1536);
  transpose_split_w<<<dim3(16, 16), 256, 0, stream>>>(Wout, woutT_h, woutT_l, 512, 512);

  // --- qkv + landmarks (+ direct vT) ---
  qkv_mfma<<<dim3(128, 12), 256, 0, stream>>>(xh, xl, wqkvT_h,
                                              q_bf, k_bf, vT, qlm, klm);

  // --- attn2 + pinv init ---
  sim2_softmax<<<8192, 256, 0, stream>>>(qlm, klm, a2h, a2l);
  colmax<<<32, 256, 0, stream>>>(a2h, red);
  finalize_scale<<<1, 64, 0, stream>>>(red);
  zinit_split<<<dim3(8, 8, 32), 256, 0, stream>>>(a2h, a2l, red,
                                                  zA_[0], zA_[1], zA_[2], zA_[3]);

  // --- pinv Newton-Schulz: launch-synchronized 3-stage chain (r3-proven).
  // Kernel boundaries provide cross-XCD coherence with full-BW refill; fused
  // in-kernel barriers measured 4x slower (r4/r5) — do not re-fuse.
  //   S1: Y = a2 @ z
  //   S2: t2 = 7Y - Y@Y ; U = z@Y     (one launch, blockIdx.z parity)
  //   S3: z' = 0.25*(13 z - 15 U + U@t2)
  // iters 0-3 plain bf16 (NS self-corrects); iter 4 split arithmetic on
  // plain-z input; iter 5 fully split.
  ush** zc = zA_;
  ush** zn = zB_;
  for (int it = 0; it < 6; ++it) {
    const bool zin_s  = (it == 5);   // z input has a valid lo plane
    const bool a2_s   = (it >= 4);   // use a2 lo plane
    const bool mid_s  = (it >= 4);   // Y/t2/U intermediates split
    const bool zout_s = (it >= 4);   // write z split
    bgemm_split<<<dim3(4, 4, 32), 256, 0, stream>>>(
        a2h, a2_s ? a2l : nullptr,
        zc[2], zin_s ? zc[3] : nullptr,
        nullptr, nullptr, nullptr, nullptr,
        Y_h, mid_s ? Y_l : nullptr, nullptr, nullptr,
        256, 256, 256, 0.f, 0.f, -1.f);
    ns_s2<<<dim3(4, 4, 64), 256, 0, stream>>>(
        Y_h, mid_s ? Y_l : nullptr,
        zc[0], zin_s ? zc[1] : nullptr,
        t2_h, mid_s ? t2_l : nullptr,
        U_h, mid_s ? U_l : nullptr);
    bgemm_split<<<dim3(4, 4, 32), 256, 0, stream>>>(
        U_h, mid_s ? U_l : nullptr,
        t2_h, mid_s ? t2_l : nullptr,
        zc[0], zin_s ? zc[1] : nullptr,      // E1 = z  (alpha = -13)
        U_h, mid_s ? U_l : nullptr,          // E2 = U  (beta  = +15)
        zn[0], zout_s ? zn[1] : nullptr,
        zn[2], zout_s ? zn[3] : nullptr,
        256, 256, 256, -13.f, 15.f, -0.25f); // y = 0.25*(13z - 15U + U@t2)
    ush** tp = zc; zc = zn; zn = tp;
  }
  // after 6 swaps zc == zA_ (attn2_inv, full split)

  // --- sim3 (flash) ---
  sim3_mfma<<<dim3(4, NCH, 32), 256, 0, stream>>>(qlm, k_bf, vT, O_part, l_part);
  sim3_finalize<<<dim3(8, 32), 256, 0, stream>>>(O_part, l_part, svB_h, svB_l);

  // --- tt = attn2_inv @ sv (write ttT = tt^T plain bf16) ---
  bgemm_split<<<dim3(4, 1, 32), 256, 0, stream>>>(
      zc[0], zc[1], svB_h, svB_l,
      nullptr, nullptr, nullptr, nullptr,
      nullptr, nullptr, ttT, nullptr, 256, 64, 256, 0.f, 0.f, -1.f);

  // --- attn1 + conv + output projection ---
  attn1_mfma<<<dim3(64, 32), 256, 0, stream>>>(q_bf, klm, ttT, outp);
  conv_add_split<<<dim3(64, 32), 256, 0, stream>>>(outp, vT, rker, outph, outpl);
  out_gemm_split<<<dim3(128, 4), 256, 0, stream>>>(outph, outpl, woutT_h, woutT_l, bout, out);
}